// Round 1
// baseline (277.412 us; speedup 1.0000x reference)
//
#include <hip/hip_runtime.h>
#include <hip/hip_bf16.h>
#include <stdint.h>
#include <type_traits>

#define NB 2
#define NS 2048
#define NDM 1024
#define NH 16
#define NHD 64
#define NTOK (NB * NS)  // 4096

typedef __bf16 bf16x8 __attribute__((ext_vector_type(8)));
typedef float f32x4 __attribute__((ext_vector_type(4)));
typedef uint16_t u16x8 __attribute__((ext_vector_type(8)));

static __device__ __forceinline__ uint16_t f2bf(float f) {
  union { float f; uint32_t u; } x; x.f = f;
  uint32_t u = x.u;
  return (uint16_t)((u + 0x7fffu + ((u >> 16) & 1u)) >> 16);  // RNE
}

static __device__ __forceinline__ u16x8 cvt8(float4 a, float4 b) {
  u16x8 v;
  v[0] = f2bf(a.x); v[1] = f2bf(a.y); v[2] = f2bf(a.z); v[3] = f2bf(a.w);
  v[4] = f2bf(b.x); v[5] = f2bf(b.y); v[6] = f2bf(b.z); v[7] = f2bf(b.w);
  return v;
}

// ---------------------------------------------------------------------------
// Shared GEMM mainloop: C[128x128] = A[128xK] * W[128xK]^T  (bt layout)
// block = 256 threads = 4 waves (2x2), each wave 64x64 (4x4 frags of 16x16)
// BK = 32, LDS padded to 40 elems/row (2-way conflicts only).
// A is fp32 (converted in staging) or bf16 (uint16_t).
// ---------------------------------------------------------------------------
template <typename AT>
static __device__ __forceinline__ void gemm_mainloop(
    const AT* __restrict__ A, const float* __restrict__ W,
    int m0, int n0, int K,
    uint16_t (*As)[40], uint16_t (*Ws)[40], f32x4 acc[4][4]) {
  int tid = threadIdx.x;
  int lane = tid & 63;
  int g = lane >> 4, r16 = lane & 15;
  int wid = tid >> 6;
  int wm = wid >> 1, wn = wid & 1;
  int srow = tid >> 2;
  int scol = (tid & 3) * 8;

  for (int k0 = 0; k0 < K; k0 += 32) {
    __syncthreads();
    #pragma unroll
    for (int p = 0; p < 2; ++p) {
      int row = p * 64 + srow;
      // A tile
      {
        u16x8 vals;
        if constexpr (std::is_same<AT, float>::value) {
          const float* src = A + (size_t)(m0 + row) * K + k0 + scol;
          float4 f0 = *(const float4*)src;
          float4 f1 = *(const float4*)(src + 4);
          vals = cvt8(f0, f1);
        } else {
          vals = *(const u16x8*)(A + (size_t)(m0 + row) * K + k0 + scol);
        }
        *(u16x8*)&As[row][scol] = vals;
      }
      // W tile (always fp32 in)
      {
        const float* src = W + (size_t)(n0 + row) * K + k0 + scol;
        float4 f0 = *(const float4*)src;
        float4 f1 = *(const float4*)(src + 4);
        *(u16x8*)&Ws[row][scol] = cvt8(f0, f1);
      }
    }
    __syncthreads();

    bf16x8 af[4], wf[4];
    #pragma unroll
    for (int i = 0; i < 4; ++i) {
      af[i] = *(const bf16x8*)&As[wm * 64 + i * 16 + r16][g * 8];
      wf[i] = *(const bf16x8*)&Ws[wn * 64 + i * 16 + r16][g * 8];
    }
    #pragma unroll
    for (int mi = 0; mi < 4; ++mi)
      #pragma unroll
      for (int ni = 0; ni < 4; ++ni)
        acc[mi][ni] = __builtin_amdgcn_mfma_f32_16x16x32_bf16(
            af[mi], wf[ni], acc[mi][ni], 0, 0, 0);
  }
}

// ---------------------------------------------------------------------------
// Projections: z=0: XQ = (q @ wq^T) * 0.125 ; z=1: XK = k @ wk^T ;
// z=2: XVT = (v @ wv^T)^T  stored as [DM][NTOK] so PV reads V^T contiguously.
// ---------------------------------------------------------------------------
__global__ __launch_bounds__(256) void proj_gemm(
    const float* __restrict__ q, const float* __restrict__ k,
    const float* __restrict__ v, const float* __restrict__ wq,
    const float* __restrict__ wk, const float* __restrict__ wv,
    uint16_t* __restrict__ XQ, uint16_t* __restrict__ XK,
    uint16_t* __restrict__ XVT) {
  __shared__ uint16_t As[128][40];
  __shared__ uint16_t Ws[128][40];
  int z = blockIdx.z;
  const float* A = (z == 0) ? q : (z == 1) ? k : v;
  const float* W = (z == 0) ? wq : (z == 1) ? wk : wv;
  int m0 = blockIdx.x * 128, n0 = blockIdx.y * 128;
  f32x4 acc[4][4] = {};
  gemm_mainloop<float>(A, W, m0, n0, NDM, As, Ws, acc);

  int lane = threadIdx.x & 63;
  int g = lane >> 4, r16 = lane & 15;
  int wid = threadIdx.x >> 6;
  int wm = wid >> 1, wn = wid & 1;
  float scale = (z == 0) ? 0.125f : 1.0f;

  #pragma unroll
  for (int mi = 0; mi < 4; ++mi) {
    #pragma unroll
    for (int ni = 0; ni < 4; ++ni) {
      int m = m0 + wm * 64 + mi * 16 + g * 4;
      int n = n0 + wn * 64 + ni * 16 + r16;
      f32x4 a = acc[mi][ni];
      if (z == 2) {
        ushort4 pk;
        pk.x = f2bf(a[0]); pk.y = f2bf(a[1]);
        pk.z = f2bf(a[2]); pk.w = f2bf(a[3]);
        *(ushort4*)&XVT[(size_t)n * NTOK + m] = pk;  // transposed store
      } else {
        uint16_t* Y = (z == 0) ? XQ : XK;
        #pragma unroll
        for (int j = 0; j < 4; ++j)
          Y[(size_t)(m + j) * NDM + n] = f2bf(a[j] * scale);
      }
    }
  }
}

// ---------------------------------------------------------------------------
// Causal flash attention. Block = 4 waves; wave w owns 16 Q rows.
// KV steps of 32; K and V^T tiles staged cooperatively in padded LDS.
// QK^T: S = mfma(Qfrag, Kfrag) twice over HD=64. Online softmax via
// 16-lane shfl_xor reductions (C rows live in reg j + lane group).
// P goes through per-wave LDS to remap C-layout -> A-layout.
// PV: Oacc[dt] = mfma(Pfrag, VTfrag[dt]).
// ---------------------------------------------------------------------------
__global__ __launch_bounds__(256) void attn_kernel(
    const uint16_t* __restrict__ XQ, const uint16_t* __restrict__ XK,
    const uint16_t* __restrict__ XVT, uint16_t* __restrict__ AO) {
  __shared__ uint16_t Klds[32][72];      // [kv][d]  stride 144B -> 2-way
  __shared__ uint16_t Vlds[64][40];      // [d][kv]  stride 80B  -> 2-way
  __shared__ uint16_t Plds[4][16][40];   // per wave [q][kv]

  int tid = threadIdx.x;
  int lane = tid & 63;
  int w = tid >> 6;
  int g = lane >> 4, r16 = lane & 15;
  int bh = blockIdx.y;
  int b = bh >> 4;   // H = 16
  int h = bh & 15;
  int q0b = blockIdx.x * 64;
  int q0 = q0b + w * 16;
  int qmax = q0 + 15;

  // Q fragments (A operand): row q0+r16, k = kc*32 + g*8
  const uint16_t* qbase =
      XQ + (size_t)(b * NS + q0 + r16) * NDM + h * NHD + g * 8;
  bf16x8 qf0 = *(const bf16x8*)(qbase);
  bf16x8 qf1 = *(const bf16x8*)(qbase + 32);

  f32x4 oacc[4] = {};  // 4 d-tiles of 16 cols; rows = g*4+j
  float mrow[4] = {-1e30f, -1e30f, -1e30f, -1e30f};
  float lrow[4] = {0.f, 0.f, 0.f, 0.f};

  int nkv = (q0b + 64) / 32;  // causal: block covers kv <= q0b+63

  int k_srow = tid >> 3, k_scol = (tid & 7) * 8;  // 32 rows x 64 cols
  int v_srow = tid >> 2, v_scol = (tid & 3) * 8;  // 64 rows x 32 cols

  for (int kb = 0; kb < nkv; ++kb) {
    int kv0 = kb * 32;
    __syncthreads();
    // stage K tile [32][64] from XK rows kv0.., head cols
    *(u16x8*)&Klds[k_srow][k_scol] = *(const u16x8*)(
        XK + (size_t)(b * NS + kv0 + k_srow) * NDM + h * NHD + k_scol);
    // stage V^T tile [64][32] from XVT
    *(u16x8*)&Vlds[v_srow][v_scol] = *(const u16x8*)(
        XVT + (size_t)(h * NHD + v_srow) * NTOK + b * NS + kv0 + v_scol);
    __syncthreads();
    if (kv0 > qmax) continue;

    // QK^T: two 16-col kv tiles
    f32x4 sc[2];
    #pragma unroll
    for (int t = 0; t < 2; ++t) {
      bf16x8 kf0 = *(const bf16x8*)&Klds[t * 16 + r16][g * 8];
      bf16x8 kf1 = *(const bf16x8*)&Klds[t * 16 + r16][32 + g * 8];
      f32x4 s = __builtin_amdgcn_mfma_f32_16x16x32_bf16(
          qf0, kf0, (f32x4){0.f, 0.f, 0.f, 0.f}, 0, 0, 0);
      s = __builtin_amdgcn_mfma_f32_16x16x32_bf16(qf1, kf1, s, 0, 0, 0);
      sc[t] = s;
    }

    // mask + online softmax; rows handled per reg j
    int kvc0 = kv0 + r16, kvc1 = kv0 + 16 + r16;
    #pragma unroll
    for (int j = 0; j < 4; ++j) {
      int qrow = q0 + g * 4 + j;
      float s0 = (kvc0 > qrow) ? -1e30f : sc[0][j];
      float s1 = (kvc1 > qrow) ? -1e30f : sc[1][j];
      float mx = fmaxf(s0, s1);
      #pragma unroll
      for (int d = 1; d < 16; d <<= 1) mx = fmaxf(mx, __shfl_xor(mx, d));
      float mnew = fmaxf(mrow[j], mx);
      float sf = __expf(mrow[j] - mnew);
      float p0 = __expf(s0 - mnew);
      float p1 = __expf(s1 - mnew);
      float rs = p0 + p1;
      #pragma unroll
      for (int d = 1; d < 16; d <<= 1) rs += __shfl_xor(rs, d);
      lrow[j] = lrow[j] * sf + rs;
      mrow[j] = mnew;
      #pragma unroll
      for (int dt = 0; dt < 4; ++dt) oacc[dt][j] *= sf;
      Plds[w][g * 4 + j][r16] = f2bf(p0);
      Plds[w][g * 4 + j][16 + r16] = f2bf(p1);
    }

    // P (A operand): row q = r16, k kv = g*8..+7
    bf16x8 pa = *(const bf16x8*)&Plds[w][r16][g * 8];
    #pragma unroll
    for (int dt = 0; dt < 4; ++dt) {
      bf16x8 vf = *(const bf16x8*)&Vlds[dt * 16 + r16][g * 8];
      oacc[dt] = __builtin_amdgcn_mfma_f32_16x16x32_bf16(pa, vf, oacc[dt], 0, 0, 0);
    }
  }

  // epilogue: normalize and store AO[token][h*64+d]
  #pragma unroll
  for (int j = 0; j < 4; ++j) {
    float inv = 1.0f / lrow[j];
    size_t rowoff = (size_t)(b * NS + q0 + g * 4 + j) * NDM + h * NHD;
    #pragma unroll
    for (int dt = 0; dt < 4; ++dt)
      AO[rowoff + dt * 16 + r16] = f2bf(oacc[dt][j] * inv);
  }
}

// ---------------------------------------------------------------------------
// Output projection: out = AO @ wo^T, fp32 out.
// ---------------------------------------------------------------------------
__global__ __launch_bounds__(256) void out_gemm(
    const uint16_t* __restrict__ AO, const float* __restrict__ wo,
    float* __restrict__ out) {
  __shared__ uint16_t As[128][40];
  __shared__ uint16_t Ws[128][40];
  int m0 = blockIdx.x * 128, n0 = blockIdx.y * 128;
  f32x4 acc[4][4] = {};
  gemm_mainloop<uint16_t>(AO, wo, m0, n0, NDM, As, Ws, acc);

  int lane = threadIdx.x & 63;
  int g = lane >> 4, r16 = lane & 15;
  int wid = threadIdx.x >> 6;
  int wm = wid >> 1, wn = wid & 1;
  #pragma unroll
  for (int mi = 0; mi < 4; ++mi) {
    #pragma unroll
    for (int ni = 0; ni < 4; ++ni) {
      int m = m0 + wm * 64 + mi * 16 + g * 4;
      int n = n0 + wn * 64 + ni * 16 + r16;
      #pragma unroll
      for (int j = 0; j < 4; ++j)
        out[(size_t)(m + j) * NDM + n] = acc[mi][ni][j];
    }
  }
}

extern "C" void kernel_launch(void* const* d_in, const int* in_sizes, int n_in,
                              void* d_out, int out_size, void* d_ws,
                              size_t ws_size, hipStream_t stream) {
  const float* q  = (const float*)d_in[0];
  const float* k  = (const float*)d_in[1];
  const float* v  = (const float*)d_in[2];
  const float* wq = (const float*)d_in[3];
  const float* wk = (const float*)d_in[4];
  const float* wv = (const float*)d_in[5];
  const float* wo = (const float*)d_in[6];

  uint16_t* XQ  = (uint16_t*)d_ws;                 // [NTOK][NDM] bf16 (pre-scaled)
  uint16_t* XK  = XQ + (size_t)NTOK * NDM;         // [NTOK][NDM]
  uint16_t* XVT = XK + (size_t)NTOK * NDM;         // [NDM][NTOK] (transposed)
  uint16_t* AO  = XVT + (size_t)NTOK * NDM;        // [NTOK][NDM]
  // total ws use: 32 MiB

  proj_gemm<<<dim3(NTOK / 128, NDM / 128, 3), 256, 0, stream>>>(
      q, k, v, wq, wk, wv, XQ, XK, XVT);
  attn_kernel<<<dim3(NS / 64, NB * NH), 256, 0, stream>>>(XQ, XK, XVT, AO);
  out_gemm<<<dim3(NTOK / 128, NDM / 128), 256, 0, stream>>>(
      AO, wo, (float*)d_out);
}

// Round 2
// 204.579 us; speedup vs baseline: 1.3560x; 1.3560x over previous
//
#include <hip/hip_runtime.h>
#include <hip/hip_bf16.h>
#include <stdint.h>
#include <type_traits>

#define NB 2
#define NS 2048
#define NDM 1024
#define NH 16
#define NHD 64
#define NTOK (NB * NS)  // 4096

typedef __bf16 bf16x8 __attribute__((ext_vector_type(8)));
typedef float f32x4 __attribute__((ext_vector_type(4)));
typedef uint16_t u16x8 __attribute__((ext_vector_type(8)));

static __device__ __forceinline__ uint16_t f2bf(float f) {
  union { float f; uint32_t u; } x; x.f = f;
  uint32_t u = x.u;
  return (uint16_t)((u + 0x7fffu + ((u >> 16) & 1u)) >> 16);  // RNE
}

static __device__ __forceinline__ u16x8 cvt8(float4 a, float4 b) {
  u16x8 v;
  v[0] = f2bf(a.x); v[1] = f2bf(a.y); v[2] = f2bf(a.z); v[3] = f2bf(a.w);
  v[4] = f2bf(b.x); v[5] = f2bf(b.y); v[6] = f2bf(b.z); v[7] = f2bf(b.w);
  return v;
}

// ---------------------------------------------------------------------------
// Shared GEMM mainloop: C[128x128] = A[128xK] * W[128xK]^T  (bt layout)
// ---------------------------------------------------------------------------
template <typename AT>
static __device__ __forceinline__ void gemm_mainloop(
    const AT* __restrict__ A, const float* __restrict__ W,
    int m0, int n0, int K,
    uint16_t (*As)[40], uint16_t (*Ws)[40], f32x4 acc[4][4]) {
  int tid = threadIdx.x;
  int lane = tid & 63;
  int g = lane >> 4, r16 = lane & 15;
  int wid = tid >> 6;
  int wm = wid >> 1, wn = wid & 1;
  int srow = tid >> 2;
  int scol = (tid & 3) * 8;

  for (int k0 = 0; k0 < K; k0 += 32) {
    __syncthreads();
    #pragma unroll
    for (int p = 0; p < 2; ++p) {
      int row = p * 64 + srow;
      {
        u16x8 vals;
        if constexpr (std::is_same<AT, float>::value) {
          const float* src = A + (size_t)(m0 + row) * K + k0 + scol;
          float4 f0 = *(const float4*)src;
          float4 f1 = *(const float4*)(src + 4);
          vals = cvt8(f0, f1);
        } else {
          vals = *(const u16x8*)(A + (size_t)(m0 + row) * K + k0 + scol);
        }
        *(u16x8*)&As[row][scol] = vals;
      }
      {
        const float* src = W + (size_t)(n0 + row) * K + k0 + scol;
        float4 f0 = *(const float4*)src;
        float4 f1 = *(const float4*)(src + 4);
        *(u16x8*)&Ws[row][scol] = cvt8(f0, f1);
      }
    }
    __syncthreads();

    bf16x8 af[4], wf[4];
    #pragma unroll
    for (int i = 0; i < 4; ++i) {
      af[i] = *(const bf16x8*)&As[wm * 64 + i * 16 + r16][g * 8];
      wf[i] = *(const bf16x8*)&Ws[wn * 64 + i * 16 + r16][g * 8];
    }
    #pragma unroll
    for (int mi = 0; mi < 4; ++mi)
      #pragma unroll
      for (int ni = 0; ni < 4; ++ni)
        acc[mi][ni] = __builtin_amdgcn_mfma_f32_16x16x32_bf16(
            af[mi], wf[ni], acc[mi][ni], 0, 0, 0);
  }
}

// ---------------------------------------------------------------------------
// Projections: z=0: XQ = (q @ wq^T) * (0.125*log2e) ; z=1: XK = k @ wk^T ;
// z=2: XVT = (v @ wv^T)^T  stored as [DM][NTOK].
// ---------------------------------------------------------------------------
__global__ __launch_bounds__(256) void proj_gemm(
    const float* __restrict__ q, const float* __restrict__ k,
    const float* __restrict__ v, const float* __restrict__ wq,
    const float* __restrict__ wk, const float* __restrict__ wv,
    uint16_t* __restrict__ XQ, uint16_t* __restrict__ XK,
    uint16_t* __restrict__ XVT) {
  __shared__ uint16_t As[128][40];
  __shared__ uint16_t Ws[128][40];
  int z = blockIdx.z;
  const float* A = (z == 0) ? q : (z == 1) ? k : v;
  const float* W = (z == 0) ? wq : (z == 1) ? wk : wv;
  int m0 = blockIdx.x * 128, n0 = blockIdx.y * 128;
  f32x4 acc[4][4] = {};
  gemm_mainloop<float>(A, W, m0, n0, NDM, As, Ws, acc);

  int lane = threadIdx.x & 63;
  int g = lane >> 4, r16 = lane & 15;
  int wid = threadIdx.x >> 6;
  int wm = wid >> 1, wn = wid & 1;
  // fold softmax scale AND log2(e) so attention uses exp2 directly
  float scale = (z == 0) ? 0.125f * 1.44269504088896340736f : 1.0f;

  #pragma unroll
  for (int mi = 0; mi < 4; ++mi) {
    #pragma unroll
    for (int ni = 0; ni < 4; ++ni) {
      int m = m0 + wm * 64 + mi * 16 + g * 4;
      int n = n0 + wn * 64 + ni * 16 + r16;
      f32x4 a = acc[mi][ni];
      if (z == 2) {
        ushort4 pk;
        pk.x = f2bf(a[0]); pk.y = f2bf(a[1]);
        pk.z = f2bf(a[2]); pk.w = f2bf(a[3]);
        *(ushort4*)&XVT[(size_t)n * NTOK + m] = pk;
      } else {
        uint16_t* Y = (z == 0) ? XQ : XK;
        #pragma unroll
        for (int j = 0; j < 4; ++j)
          Y[(size_t)(m + j) * NDM + n] = f2bf(a[j] * scale);
      }
    }
  }
}

// ---------------------------------------------------------------------------
// Causal flash attention v2.
// Block = 4 waves x 32 q-rows (two 16-row sub-tiles) = 128 q rows.
// KVBLK = 64, single LDS buffer, T14 async-stage (loads issued before compute,
// written to LDS after barrier next iteration). Heavy-first block order.
// Softmax: max-reduce per iter (4 shfl), SUM deferred to epilogue (per-lane
// partials). Masking only on wave-uniform diagonal iterations. exp2 domain.
// ---------------------------------------------------------------------------
__global__ __launch_bounds__(256) void attn_kernel(
    const uint16_t* __restrict__ XQ, const uint16_t* __restrict__ XK,
    const uint16_t* __restrict__ XVT, uint16_t* __restrict__ AO) {
  __shared__ uint16_t Klds[64][72];        // [kv][d]
  __shared__ uint16_t Vlds[64][72];        // [d][kv]
  __shared__ uint16_t Plds[4][2][16][72];  // per wave, per sub-tile [q][kv]

  int tid = threadIdx.x;
  int lane = tid & 63;
  int w = tid >> 6;
  int g = lane >> 4, r16 = lane & 15;
  int bh = blockIdx.y;
  int b = bh >> 4, h = bh & 15;
  int qc = (int)gridDim.x - 1 - (int)blockIdx.x;  // heaviest chunk first
  int q0b = qc * 128;
  int q0w = q0b + w * 32;

  // Q fragments (A operand), pre-scaled by 0.125*log2e at projection
  bf16x8 qf[2][2];
  #pragma unroll
  for (int s = 0; s < 2; ++s) {
    const uint16_t* qb =
        XQ + (size_t)(b * NS + q0w + s * 16 + r16) * NDM + h * NHD + g * 8;
    qf[s][0] = *(const bf16x8*)qb;
    qf[s][1] = *(const bf16x8*)(qb + 32);
  }

  f32x4 oacc[2][4] = {};
  float mrow[2][4], lsum[2][4];
  #pragma unroll
  for (int s = 0; s < 2; ++s)
    #pragma unroll
    for (int j = 0; j < 4; ++j) { mrow[s][j] = -1e30f; lsum[s][j] = 0.f; }

  int srow = tid >> 2;          // 0..63
  int scol = (tid & 3) * 16;    // 0,16,32,48
  int T = (q0b + 128) / 64;

  const uint16_t* kbase = XK + (size_t)(b * NS + srow) * NDM + h * NHD + scol;
  const uint16_t* vbase = XVT + (size_t)(h * NHD + srow) * NTOK + b * NS + scol;

  // prefetch tile 0 into registers
  u16x8 kr0 = *(const u16x8*)(kbase);
  u16x8 kr1 = *(const u16x8*)(kbase + 8);
  u16x8 vr0 = *(const u16x8*)(vbase);
  u16x8 vr1 = *(const u16x8*)(vbase + 8);

  for (int t = 0; t < T; ++t) {
    int kv0 = t * 64;
    __syncthreads();  // all waves done reading LDS tile t-1
    *(u16x8*)&Klds[srow][scol]     = kr0;
    *(u16x8*)&Klds[srow][scol + 8] = kr1;
    *(u16x8*)&Vlds[srow][scol]     = vr0;
    *(u16x8*)&Vlds[srow][scol + 8] = vr1;
    __syncthreads();
    if (t + 1 < T) {  // issue next tile's loads; compute hides the latency
      const uint16_t* kp = kbase + (size_t)(t + 1) * 64 * NDM;
      const uint16_t* vp = vbase + (t + 1) * 64;
      kr0 = *(const u16x8*)(kp);
      kr1 = *(const u16x8*)(kp + 8);
      vr0 = *(const u16x8*)(vp);
      vr1 = *(const u16x8*)(vp + 8);
    }
    if (kv0 > q0w + 31) continue;  // wave-uniform causal skip

    // ---- QK^T: S[32q][64kv] per wave ----
    f32x4 sc[2][4];
    #pragma unroll
    for (int t4 = 0; t4 < 4; ++t4) {
      bf16x8 kf0 = *(const bf16x8*)&Klds[t4 * 16 + r16][g * 8];
      bf16x8 kf1 = *(const bf16x8*)&Klds[t4 * 16 + r16][32 + g * 8];
      #pragma unroll
      for (int s = 0; s < 2; ++s) {
        f32x4 x = __builtin_amdgcn_mfma_f32_16x16x32_bf16(
            qf[s][0], kf0, (f32x4){0.f, 0.f, 0.f, 0.f}, 0, 0, 0);
        x = __builtin_amdgcn_mfma_f32_16x16x32_bf16(qf[s][1], kf1, x, 0, 0, 0);
        sc[s][t4] = x;
      }
    }

    bool diag = (kv0 + 63 > q0w);  // wave-uniform: mask only near diagonal
    #pragma unroll
    for (int s = 0; s < 2; ++s) {
      int qr0 = q0w + s * 16;
      if (diag) {
        #pragma unroll
        for (int t4 = 0; t4 < 4; ++t4) {
          int kvc = kv0 + t4 * 16 + r16;
          #pragma unroll
          for (int j = 0; j < 4; ++j)
            if (kvc > qr0 + g * 4 + j) sc[s][t4][j] = -1e30f;
        }
      }
      #pragma unroll
      for (int j = 0; j < 4; ++j) {
        float m4 = fmaxf(fmaxf(sc[s][0][j], sc[s][1][j]),
                         fmaxf(sc[s][2][j], sc[s][3][j]));
        #pragma unroll
        for (int d = 1; d < 16; d <<= 1) m4 = fmaxf(m4, __shfl_xor(m4, d));
        float mnew = fmaxf(mrow[s][j], m4);
        float sf = __builtin_amdgcn_exp2f(mrow[s][j] - mnew);
        mrow[s][j] = mnew;
        float p0 = __builtin_amdgcn_exp2f(sc[s][0][j] - mnew);
        float p1 = __builtin_amdgcn_exp2f(sc[s][1][j] - mnew);
        float p2 = __builtin_amdgcn_exp2f(sc[s][2][j] - mnew);
        float p3 = __builtin_amdgcn_exp2f(sc[s][3][j] - mnew);
        lsum[s][j] = lsum[s][j] * sf + ((p0 + p1) + (p2 + p3));  // per-lane partial
        #pragma unroll
        for (int dt = 0; dt < 4; ++dt) oacc[s][dt][j] *= sf;
        int ql = g * 4 + j;
        Plds[w][s][ql][r16]      = f2bf(p0);
        Plds[w][s][ql][16 + r16] = f2bf(p1);
        Plds[w][s][ql][32 + r16] = f2bf(p2);
        Plds[w][s][ql][48 + r16] = f2bf(p3);
      }
    }

    // ---- PV: O += P[32q][64kv] @ V^T ----
    bf16x8 pa[2][2];
    #pragma unroll
    for (int s = 0; s < 2; ++s) {
      pa[s][0] = *(const bf16x8*)&Plds[w][s][r16][g * 8];
      pa[s][1] = *(const bf16x8*)&Plds[w][s][r16][32 + g * 8];
    }
    #pragma unroll
    for (int dt = 0; dt < 4; ++dt) {
      bf16x8 vf0 = *(const bf16x8*)&Vlds[dt * 16 + r16][g * 8];
      bf16x8 vf1 = *(const bf16x8*)&Vlds[dt * 16 + r16][32 + g * 8];
      #pragma unroll
      for (int s = 0; s < 2; ++s) {
        oacc[s][dt] = __builtin_amdgcn_mfma_f32_16x16x32_bf16(
            pa[s][0], vf0, oacc[s][dt], 0, 0, 0);
        oacc[s][dt] = __builtin_amdgcn_mfma_f32_16x16x32_bf16(
            pa[s][1], vf1, oacc[s][dt], 0, 0, 0);
      }
    }
  }

  // ---- epilogue: finish deferred sum reduce, normalize, store ----
  #pragma unroll
  for (int s = 0; s < 2; ++s) {
    #pragma unroll
    for (int j = 0; j < 4; ++j) {
      float lt = lsum[s][j];
      #pragma unroll
      for (int d = 1; d < 16; d <<= 1) lt += __shfl_xor(lt, d);
      float inv = 1.0f / lt;
      size_t ro = (size_t)(b * NS + q0w + s * 16 + g * 4 + j) * NDM + h * NHD;
      #pragma unroll
      for (int dt = 0; dt < 4; ++dt)
        AO[ro + dt * 16 + r16] = f2bf(oacc[s][dt][j] * inv);
    }
  }
}

// ---------------------------------------------------------------------------
// Output projection: out = AO @ wo^T, fp32 out.
// ---------------------------------------------------------------------------
__global__ __launch_bounds__(256) void out_gemm(
    const uint16_t* __restrict__ AO, const float* __restrict__ wo,
    float* __restrict__ out) {
  __shared__ uint16_t As[128][40];
  __shared__ uint16_t Ws[128][40];
  int m0 = blockIdx.x * 128, n0 = blockIdx.y * 128;
  f32x4 acc[4][4] = {};
  gemm_mainloop<uint16_t>(AO, wo, m0, n0, NDM, As, Ws, acc);

  int lane = threadIdx.x & 63;
  int g = lane >> 4, r16 = lane & 15;
  int wid = threadIdx.x >> 6;
  int wm = wid >> 1, wn = wid & 1;
  #pragma unroll
  for (int mi = 0; mi < 4; ++mi) {
    #pragma unroll
    for (int ni = 0; ni < 4; ++ni) {
      int m = m0 + wm * 64 + mi * 16 + g * 4;
      int n = n0 + wn * 64 + ni * 16 + r16;
      #pragma unroll
      for (int j = 0; j < 4; ++j)
        out[(size_t)(m + j) * NDM + n] = acc[mi][ni][j];
    }
  }
}

extern "C" void kernel_launch(void* const* d_in, const int* in_sizes, int n_in,
                              void* d_out, int out_size, void* d_ws,
                              size_t ws_size, hipStream_t stream) {
  const float* q  = (const float*)d_in[0];
  const float* k  = (const float*)d_in[1];
  const float* v  = (const float*)d_in[2];
  const float* wq = (const float*)d_in[3];
  const float* wk = (const float*)d_in[4];
  const float* wv = (const float*)d_in[5];
  const float* wo = (const float*)d_in[6];

  uint16_t* XQ  = (uint16_t*)d_ws;                 // [NTOK][NDM] bf16 (pre-scaled)
  uint16_t* XK  = XQ + (size_t)NTOK * NDM;         // [NTOK][NDM]
  uint16_t* XVT = XK + (size_t)NTOK * NDM;         // [NDM][NTOK] (transposed)
  uint16_t* AO  = XVT + (size_t)NTOK * NDM;        // [NTOK][NDM]

  proj_gemm<<<dim3(NTOK / 128, NDM / 128, 3), 256, 0, stream>>>(
      q, k, v, wq, wk, wv, XQ, XK, XVT);
  attn_kernel<<<dim3(NS / 128, NB * NH), 256, 0, stream>>>(XQ, XK, XVT, AO);
  out_gemm<<<dim3(NTOK / 128, NDM / 128), 256, 0, stream>>>(
      AO, wo, (float*)d_out);
}

// Round 3
// 153.307 us; speedup vs baseline: 1.8095x; 1.3344x over previous
//
#include <hip/hip_runtime.h>
#include <hip/hip_bf16.h>
#include <stdint.h>

#define NB 2
#define NS 2048
#define NDM 1024
#define NH 16
#define NHD 64
#define NTOK (NB * NS)  // 4096

typedef __bf16 bf16x8 __attribute__((ext_vector_type(8)));
typedef float f32x4 __attribute__((ext_vector_type(4)));
typedef uint16_t u16x8 __attribute__((ext_vector_type(8)));

static __device__ __forceinline__ uint16_t f2bf(float f) {
  __bf16 b = (__bf16)f;  // RNE, lowers to v_cvt_pk_bf16_f32
  union { __bf16 b; uint16_t u; } x; x.b = b;
  return x.u;
}

static __device__ __forceinline__ u16x8 cvt8(float4 a, float4 b) {
  u16x8 v;
  v[0] = f2bf(a.x); v[1] = f2bf(a.y); v[2] = f2bf(a.z); v[3] = f2bf(a.w);
  v[4] = f2bf(b.x); v[5] = f2bf(b.y); v[6] = f2bf(b.z); v[7] = f2bf(b.w);
  return v;
}

// async global->LDS, 16B per lane, wave-linear LDS destination
static __device__ __forceinline__ void gload_lds16(const void* g, void* l) {
  __builtin_amdgcn_global_load_lds(
      (const __attribute__((address_space(1))) void*)g,
      (__attribute__((address_space(3))) void*)l, 16, 0, 0);
}

// 16-lane (DPP row) reductions: rotate-reduce, all lanes get result
template <int CTRL>
static __device__ __forceinline__ float dppmax(float x) {
  int y = __builtin_amdgcn_update_dpp(0, __float_as_int(x), CTRL, 0xF, 0xF, true);
  return fmaxf(x, __int_as_float(y));
}
static __device__ __forceinline__ float rowmax16(float x) {
  x = dppmax<0x128>(x);  // row_ror:8
  x = dppmax<0x124>(x);  // row_ror:4
  x = dppmax<0x122>(x);  // row_ror:2
  x = dppmax<0x121>(x);  // row_ror:1
  return x;
}
template <int CTRL>
static __device__ __forceinline__ float dppadd(float x) {
  int y = __builtin_amdgcn_update_dpp(0, __float_as_int(x), CTRL, 0xF, 0xF, true);
  return x + __int_as_float(y);
}
static __device__ __forceinline__ float rowsum16(float x) {
  x = dppadd<0x128>(x);
  x = dppadd<0x124>(x);
  x = dppadd<0x122>(x);
  x = dppadd<0x121>(x);
  return x;
}

// ---------------------------------------------------------------------------
// Weight fp32 -> bf16 convert (wq,wk,wv,wo), 1M elems each.
// ---------------------------------------------------------------------------
__global__ __launch_bounds__(256) void cvt_w(
    const float* __restrict__ w0, const float* __restrict__ w1,
    const float* __restrict__ w2, const float* __restrict__ w3,
    uint16_t* __restrict__ o0, uint16_t* __restrict__ o1,
    uint16_t* __restrict__ o2, uint16_t* __restrict__ o3) {
  int y = blockIdx.y;
  const float* src = (y == 0) ? w0 : (y == 1) ? w1 : (y == 2) ? w2 : w3;
  uint16_t* dst = (y == 0) ? o0 : (y == 1) ? o1 : (y == 2) ? o2 : o3;
  int i = ((int)blockIdx.x * 256 + (int)threadIdx.x) * 8;
  float4 a = *(const float4*)(src + i);
  float4 b = *(const float4*)(src + i + 4);
  *(u16x8*)&dst[i] = cvt8(a, b);
}

// ---------------------------------------------------------------------------
// Projections: C[128x128] tile of X @ W^T.  A = fp32 activation (reg-staged,
// cvt to bf16, padded LDS -> conflict-free A reads).  B = bf16 weights via
// global_load_lds (linear LDS).  BK=64, 32 MFMA / K-step, 2-barrier loop.
// z=0: XQ scaled by 0.125*log2e ; z=1: XK ; z=2: XVT (transposed store).
// ---------------------------------------------------------------------------
__global__ __launch_bounds__(256) void proj_gemm(
    const float* __restrict__ q, const float* __restrict__ k,
    const float* __restrict__ v, const uint16_t* __restrict__ wqb,
    const uint16_t* __restrict__ wkb, const uint16_t* __restrict__ wvb,
    uint16_t* __restrict__ XQ, uint16_t* __restrict__ XK,
    uint16_t* __restrict__ XVT) {
  __shared__ uint16_t As[128][72];  // padded: conflict-free frag reads
  __shared__ uint16_t Bs[128][64];  // linear: global_load_lds target
  int z = blockIdx.z;
  const float* A = (z == 0) ? q : (z == 1) ? k : v;
  const uint16_t* W = (z == 0) ? wqb : (z == 1) ? wkb : wvb;
  int m0 = blockIdx.x * 128, n0 = blockIdx.y * 128;
  int tid = threadIdx.x;
  int lane = tid & 63, w = tid >> 6;
  int g = lane >> 4, r16 = lane & 15;
  int wm = w >> 1, wn = w & 1;

  f32x4 acc[4][4] = {};

  for (int k0 = 0; k0 < NDM; k0 += 64) {
    __syncthreads();  // prior readers done
    // B tile: 4 x 1KB async loads per wave (8 rows each)
    #pragma unroll
    for (int i = 0; i < 4; ++i) {
      int brow = w * 32 + i * 8;
      const uint16_t* src =
          W + (size_t)(n0 + brow + (lane >> 3)) * NDM + k0 + (lane & 7) * 8;
      gload_lds16(src, &Bs[brow][0]);
    }
    // A tile: fp32 load + cvt + padded ds_write (chunk-linear assignment)
    #pragma unroll
    for (int cc = 0; cc < 4; ++cc) {
      int ch = tid + cc * 256;        // 1024 chunks = 128 rows x 8
      int row = ch >> 3, c8 = ch & 7;
      const float* src = A + (size_t)(m0 + row) * NDM + k0 + c8 * 8;
      float4 f0 = *(const float4*)src;
      float4 f1 = *(const float4*)(src + 4);
      *(u16x8*)&As[row][c8 * 8] = cvt8(f0, f1);
    }
    __syncthreads();  // drains vmcnt (gload) + lgkm (ds_write)

    #pragma unroll
    for (int kc = 0; kc < 2; ++kc) {
      bf16x8 af[4], bf[4];
      #pragma unroll
      for (int i = 0; i < 4; ++i) {
        af[i] = *(const bf16x8*)&As[wm * 64 + i * 16 + r16][kc * 32 + g * 8];
        bf[i] = *(const bf16x8*)&Bs[wn * 64 + i * 16 + r16][kc * 32 + g * 8];
      }
      #pragma unroll
      for (int mi = 0; mi < 4; ++mi)
        #pragma unroll
        for (int ni = 0; ni < 4; ++ni)
          acc[mi][ni] = __builtin_amdgcn_mfma_f32_16x16x32_bf16(
              af[mi], bf[ni], acc[mi][ni], 0, 0, 0);
    }
  }

  float scale = (z == 0) ? 0.125f * 1.44269504088896340736f : 1.0f;
  #pragma unroll
  for (int mi = 0; mi < 4; ++mi) {
    #pragma unroll
    for (int ni = 0; ni < 4; ++ni) {
      int m = m0 + wm * 64 + mi * 16 + g * 4;
      int n = n0 + wn * 64 + ni * 16 + r16;
      f32x4 a = acc[mi][ni];
      if (z == 2) {
        ushort4 pk;
        pk.x = f2bf(a[0]); pk.y = f2bf(a[1]);
        pk.z = f2bf(a[2]); pk.w = f2bf(a[3]);
        *(ushort4*)&XVT[(size_t)n * NTOK + m] = pk;  // transposed store
      } else {
        uint16_t* Y = (z == 0) ? XQ : XK;
        #pragma unroll
        for (int j = 0; j < 4; ++j)
          Y[(size_t)(m + j) * NDM + n] = f2bf(a[j] * scale);
      }
    }
  }
}

// ---------------------------------------------------------------------------
// Causal flash attention v3.
// 1024 items = 32 q-chunks(64 rows) x 32 (b,h).  512 blocks; block c does
// items 1023-c then c  -> per-block work exactly constant (snake pairing).
// Block = 4 waves x 16 q rows.  KVBLK=64, reg prefetch (T14), DPP softmax
// reductions, defer-rescale (T13), setprio around MFMA (T5).
// ---------------------------------------------------------------------------
__global__ __launch_bounds__(256) void attn_kernel(
    const uint16_t* __restrict__ XQ, const uint16_t* __restrict__ XK,
    const uint16_t* __restrict__ XVT, uint16_t* __restrict__ AO) {
  __shared__ uint16_t Klds[64][72];   // [kv][d]
  __shared__ uint16_t Vlds[64][72];   // [d][kv]
  __shared__ uint16_t Plds[4][16][72];

  int tid = threadIdx.x;
  int lane = tid & 63;
  int w = tid >> 6;
  int g = lane >> 4, r16 = lane & 15;
  int srow = tid >> 2;          // staging: 0..63
  int scol = (tid & 3) * 16;    // 0,16,32,48

  #pragma unroll
  for (int which = 0; which < 2; ++which) {
    int item = (which == 0) ? (1023 - (int)blockIdx.x) : (int)blockIdx.x;
    int qc = item >> 5;         // 0..31, chunk of 64 q rows
    int bh = item & 31;
    int b = bh >> 4, h = bh & 15;
    int q0 = qc * 64;
    int q0w = q0 + w * 16;
    int T = qc + 1;             // kv tiles of 64

    // Q fragments (A operand), pre-scaled by 0.125*log2e
    const uint16_t* qb =
        XQ + (size_t)(b * NS + q0w + r16) * NDM + h * NHD + g * 8;
    bf16x8 qf0 = *(const bf16x8*)qb;
    bf16x8 qf1 = *(const bf16x8*)(qb + 32);

    f32x4 oacc[4] = {};
    float mrow[4] = {-1e30f, -1e30f, -1e30f, -1e30f};
    float lsum[4] = {0.f, 0.f, 0.f, 0.f};

    const uint16_t* kbase =
        XK + (size_t)(b * NS + srow) * NDM + h * NHD + scol;
    const uint16_t* vbase =
        XVT + (size_t)(h * NHD + srow) * NTOK + b * NS + scol;

    u16x8 kr0 = *(const u16x8*)(kbase);
    u16x8 kr1 = *(const u16x8*)(kbase + 8);
    u16x8 vr0 = *(const u16x8*)(vbase);
    u16x8 vr1 = *(const u16x8*)(vbase + 8);

    for (int t = 0; t < T; ++t) {
      int kv0 = t * 64;
      __syncthreads();  // all waves done reading previous LDS tile
      *(u16x8*)&Klds[srow][scol]     = kr0;
      *(u16x8*)&Klds[srow][scol + 8] = kr1;
      *(u16x8*)&Vlds[srow][scol]     = vr0;
      *(u16x8*)&Vlds[srow][scol + 8] = vr1;
      __syncthreads();
      if (t + 1 < T) {  // prefetch next tile; compute hides latency
        const uint16_t* kp = kbase + (size_t)(t + 1) * 64 * NDM;
        const uint16_t* vp = vbase + (t + 1) * 64;
        kr0 = *(const u16x8*)(kp);
        kr1 = *(const u16x8*)(kp + 8);
        vr0 = *(const u16x8*)(vp);
        vr1 = *(const u16x8*)(vp + 8);
      }
      if (kv0 > q0w + 15) continue;  // wave-uniform causal skip

      // ---- QK^T: S[16q][64kv] ----
      f32x4 sc[4];
      __builtin_amdgcn_s_setprio(1);
      #pragma unroll
      for (int t4 = 0; t4 < 4; ++t4) {
        bf16x8 kf0 = *(const bf16x8*)&Klds[t4 * 16 + r16][g * 8];
        bf16x8 kf1 = *(const bf16x8*)&Klds[t4 * 16 + r16][32 + g * 8];
        f32x4 x = __builtin_amdgcn_mfma_f32_16x16x32_bf16(
            qf0, kf0, (f32x4){0.f, 0.f, 0.f, 0.f}, 0, 0, 0);
        x = __builtin_amdgcn_mfma_f32_16x16x32_bf16(qf1, kf1, x, 0, 0, 0);
        sc[t4] = x;
      }
      __builtin_amdgcn_s_setprio(0);

      // ---- mask (diag tiles only) ----
      #pragma unroll
      for (int t4 = 0; t4 < 4; ++t4) {
        if (kv0 + t4 * 16 + 15 > q0w) {  // wave-uniform guard
          int kvc = kv0 + t4 * 16 + r16;
          #pragma unroll
          for (int j = 0; j < 4; ++j)
            if (kvc > q0w + g * 4 + j) sc[t4][j] = -1e30f;
        }
      }

      // ---- online softmax, DPP reduce + defer-rescale ----
      #pragma unroll
      for (int j = 0; j < 4; ++j) {
        float m4 = fmaxf(fmaxf(sc[0][j], sc[1][j]),
                         fmaxf(sc[2][j], sc[3][j]));
        m4 = rowmax16(m4);
        float p0, p1, p2, p3;
        if (__all(m4 <= mrow[j])) {  // no growth anywhere: skip rescale
          p0 = __builtin_amdgcn_exp2f(sc[0][j] - mrow[j]);
          p1 = __builtin_amdgcn_exp2f(sc[1][j] - mrow[j]);
          p2 = __builtin_amdgcn_exp2f(sc[2][j] - mrow[j]);
          p3 = __builtin_amdgcn_exp2f(sc[3][j] - mrow[j]);
          lsum[j] += (p0 + p1) + (p2 + p3);
        } else {
          float mnew = fmaxf(mrow[j], m4);
          float sf = __builtin_amdgcn_exp2f(mrow[j] - mnew);
          mrow[j] = mnew;
          p0 = __builtin_amdgcn_exp2f(sc[0][j] - mnew);
          p1 = __builtin_amdgcn_exp2f(sc[1][j] - mnew);
          p2 = __builtin_amdgcn_exp2f(sc[2][j] - mnew);
          p3 = __builtin_amdgcn_exp2f(sc[3][j] - mnew);
          lsum[j] = lsum[j] * sf + ((p0 + p1) + (p2 + p3));
          #pragma unroll
          for (int dt = 0; dt < 4; ++dt) oacc[dt][j] *= sf;
        }
        int ql = g * 4 + j;
        Plds[w][ql][r16]      = f2bf(p0);
        Plds[w][ql][16 + r16] = f2bf(p1);
        Plds[w][ql][32 + r16] = f2bf(p2);
        Plds[w][ql][48 + r16] = f2bf(p3);
      }

      // ---- PV ----
      bf16x8 pa0 = *(const bf16x8*)&Plds[w][r16][g * 8];
      bf16x8 pa1 = *(const bf16x8*)&Plds[w][r16][32 + g * 8];
      __builtin_amdgcn_s_setprio(1);
      #pragma unroll
      for (int dt = 0; dt < 4; ++dt) {
        bf16x8 vf0 = *(const bf16x8*)&Vlds[dt * 16 + r16][g * 8];
        bf16x8 vf1 = *(const bf16x8*)&Vlds[dt * 16 + r16][32 + g * 8];
        oacc[dt] = __builtin_amdgcn_mfma_f32_16x16x32_bf16(pa0, vf0, oacc[dt], 0, 0, 0);
        oacc[dt] = __builtin_amdgcn_mfma_f32_16x16x32_bf16(pa1, vf1, oacc[dt], 0, 0, 0);
      }
      __builtin_amdgcn_s_setprio(0);
    }

    // ---- epilogue ----
    #pragma unroll
    for (int j = 0; j < 4; ++j) {
      float lt = rowsum16(lsum[j]);
      float inv = 1.0f / lt;
      size_t ro = (size_t)(b * NS + q0w + g * 4 + j) * NDM + h * NHD;
      #pragma unroll
      for (int dt = 0; dt < 4; ++dt)
        AO[ro + dt * 16 + r16] = f2bf(oacc[dt][j] * inv);
    }
  }
}

// ---------------------------------------------------------------------------
// Output projection: out = AO @ wo^T (fp32 out). Both operands bf16 via
// global_load_lds, linear LDS, BK=64 (m97 structure).
// ---------------------------------------------------------------------------
__global__ __launch_bounds__(256) void out_gemm(
    const uint16_t* __restrict__ AO, const uint16_t* __restrict__ wob,
    float* __restrict__ out) {
  __shared__ uint16_t As[128][64];
  __shared__ uint16_t Bs[128][64];
  int m0 = blockIdx.x * 128, n0 = blockIdx.y * 128;
  int tid = threadIdx.x;
  int lane = tid & 63, w = tid >> 6;
  int g = lane >> 4, r16 = lane & 15;
  int wm = w >> 1, wn = w & 1;

  f32x4 acc[4][4] = {};

  for (int k0 = 0; k0 < NDM; k0 += 64) {
    __syncthreads();
    #pragma unroll
    for (int i = 0; i < 4; ++i) {
      int row = w * 32 + i * 8;
      const uint16_t* asrc =
          AO + (size_t)(m0 + row + (lane >> 3)) * NDM + k0 + (lane & 7) * 8;
      gload_lds16(asrc, &As[row][0]);
      const uint16_t* bsrc =
          wob + (size_t)(n0 + row + (lane >> 3)) * NDM + k0 + (lane & 7) * 8;
      gload_lds16(bsrc, &Bs[row][0]);
    }
    __syncthreads();

    #pragma unroll
    for (int kc = 0; kc < 2; ++kc) {
      bf16x8 af[4], bf[4];
      #pragma unroll
      for (int i = 0; i < 4; ++i) {
        af[i] = *(const bf16x8*)&As[wm * 64 + i * 16 + r16][kc * 32 + g * 8];
        bf[i] = *(const bf16x8*)&Bs[wn * 64 + i * 16 + r16][kc * 32 + g * 8];
      }
      #pragma unroll
      for (int mi = 0; mi < 4; ++mi)
        #pragma unroll
        for (int ni = 0; ni < 4; ++ni)
          acc[mi][ni] = __builtin_amdgcn_mfma_f32_16x16x32_bf16(
              af[mi], bf[ni], acc[mi][ni], 0, 0, 0);
    }
  }

  #pragma unroll
  for (int mi = 0; mi < 4; ++mi) {
    #pragma unroll
    for (int ni = 0; ni < 4; ++ni) {
      int m = m0 + wm * 64 + mi * 16 + g * 4;
      int n = n0 + wn * 64 + ni * 16 + r16;
      #pragma unroll
      for (int j = 0; j < 4; ++j)
        out[(size_t)(m + j) * NDM + n] = acc[mi][ni][j];
    }
  }
}

extern "C" void kernel_launch(void* const* d_in, const int* in_sizes, int n_in,
                              void* d_out, int out_size, void* d_ws,
                              size_t ws_size, hipStream_t stream) {
  const float* q  = (const float*)d_in[0];
  const float* k  = (const float*)d_in[1];
  const float* v  = (const float*)d_in[2];
  const float* wq = (const float*)d_in[3];
  const float* wk = (const float*)d_in[4];
  const float* wv = (const float*)d_in[5];
  const float* wo = (const float*)d_in[6];

  uint16_t* XQ  = (uint16_t*)d_ws;                 // [NTOK][NDM] bf16
  uint16_t* XK  = XQ + (size_t)NTOK * NDM;         // [NTOK][NDM]
  uint16_t* XVT = XK + (size_t)NTOK * NDM;         // [NDM][NTOK]
  uint16_t* AO  = XVT + (size_t)NTOK * NDM;        // [NTOK][NDM]
  uint16_t* WQB = AO + (size_t)NTOK * NDM;         // [NDM][NDM] bf16 weights
  uint16_t* WKB = WQB + (size_t)NDM * NDM;
  uint16_t* WVB = WKB + (size_t)NDM * NDM;
  uint16_t* WOB = WVB + (size_t)NDM * NDM;
  // total ws use: 40 MiB

  cvt_w<<<dim3(NDM * NDM / (256 * 8), 4), 256, 0, stream>>>(
      wq, wk, wv, wo, WQB, WKB, WVB, WOB);
  proj_gemm<<<dim3(NTOK / 128, NDM / 128, 3), 256, 0, stream>>>(
      q, k, v, WQB, WKB, WVB, XQ, XK, XVT);
  attn_kernel<<<dim3(512), 256, 0, stream>>>(XQ, XK, XVT, AO);
  out_gemm<<<dim3(NTOK / 128, NDM / 128), 256, 0, stream>>>(
      AO, WOB, (float*)d_out);
}

// Round 4
// 131.470 us; speedup vs baseline: 2.1101x; 1.1661x over previous
//
#include <hip/hip_runtime.h>
#include <hip/hip_bf16.h>
#include <stdint.h>

#define NB 2
#define NS 2048
#define NDM 1024
#define NH 16
#define NHD 64
#define NTOK (NB * NS)  // 4096

typedef __bf16 bf16x8 __attribute__((ext_vector_type(8)));
typedef float f32x4 __attribute__((ext_vector_type(4)));
typedef uint16_t u16x8 __attribute__((ext_vector_type(8)));

static __device__ __forceinline__ uint16_t f2bf(float f) {
  __bf16 b = (__bf16)f;  // RNE, lowers to v_cvt_pk_bf16_f32 when paired
  union { __bf16 b; uint16_t u; } x; x.b = b;
  return x.u;
}

static __device__ __forceinline__ u16x8 cvt8(float4 a, float4 b) {
  u16x8 v;
  v[0] = f2bf(a.x); v[1] = f2bf(a.y); v[2] = f2bf(a.z); v[3] = f2bf(a.w);
  v[4] = f2bf(b.x); v[5] = f2bf(b.y); v[6] = f2bf(b.z); v[7] = f2bf(b.w);
  return v;
}

// async global->LDS, 16B per lane, wave-linear LDS destination
static __device__ __forceinline__ void gload_lds16(const void* g, void* l) {
  __builtin_amdgcn_global_load_lds(
      (const __attribute__((address_space(1))) void*)g,
      (__attribute__((address_space(3))) void*)l, 16, 0, 0);
}

// ---------------------------------------------------------------------------
// Weight fp32 -> bf16 convert (wq,wk,wv,wo), 1M elems each.
// ---------------------------------------------------------------------------
__global__ __launch_bounds__(256) void cvt_w(
    const float* __restrict__ w0, const float* __restrict__ w1,
    const float* __restrict__ w2, const float* __restrict__ w3,
    uint16_t* __restrict__ o0, uint16_t* __restrict__ o1,
    uint16_t* __restrict__ o2, uint16_t* __restrict__ o3) {
  int y = blockIdx.y;
  const float* src = (y == 0) ? w0 : (y == 1) ? w1 : (y == 2) ? w2 : w3;
  uint16_t* dst = (y == 0) ? o0 : (y == 1) ? o1 : (y == 2) ? o2 : o3;
  int i = ((int)blockIdx.x * 256 + (int)threadIdx.x) * 8;
  float4 a = *(const float4*)(src + i);
  float4 b = *(const float4*)(src + i + 4);
  *(u16x8*)&dst[i] = cvt8(a, b);
}

// ---------------------------------------------------------------------------
// Projections: C[128x128] tile of X @ W^T.
// A = fp32 activation, T14 async-stage: regs loaded one K-step ahead (issued
// right after the 2nd barrier, consumed at the next iteration's ds_write) so
// HBM latency hides under the 32-MFMA phase.  B = bf16 weights via
// global_load_lds.  BK=64.
// z=0: XQ scaled by 0.125*log2e ; z=1: XK ; z=2: XVT (transposed store).
// ---------------------------------------------------------------------------
__global__ __launch_bounds__(256) void proj_gemm(
    const float* __restrict__ q, const float* __restrict__ k,
    const float* __restrict__ v, const uint16_t* __restrict__ wqb,
    const uint16_t* __restrict__ wkb, const uint16_t* __restrict__ wvb,
    uint16_t* __restrict__ XQ, uint16_t* __restrict__ XK,
    uint16_t* __restrict__ XVT) {
  __shared__ uint16_t As[128][72];  // padded: conflict-free frag reads
  __shared__ uint16_t Bs[128][64];  // linear: global_load_lds target
  int z = blockIdx.z;
  const float* A = (z == 0) ? q : (z == 1) ? k : v;
  const uint16_t* W = (z == 0) ? wqb : (z == 1) ? wkb : wvb;
  int m0 = blockIdx.x * 128, n0 = blockIdx.y * 128;
  int tid = threadIdx.x;
  int lane = tid & 63, w = tid >> 6;
  int g = lane >> 4, r16 = lane & 15;
  int wm = w >> 1, wn = w & 1;

  f32x4 acc[4][4] = {};
  float4 a0[4], a1[4];  // prefetched A chunks (one K-step ahead)

  // prologue: load A(k0=0)
  #pragma unroll
  for (int cc = 0; cc < 4; ++cc) {
    int ch = tid + cc * 256;
    int row = ch >> 3, c8 = ch & 7;
    const float* src = A + (size_t)(m0 + row) * NDM + c8 * 8;
    a0[cc] = *(const float4*)src;
    a1[cc] = *(const float4*)(src + 4);
  }

  for (int k0 = 0; k0 < NDM; k0 += 64) {
    __syncthreads();  // prior readers done
    // A tile: cvt prefetched regs -> padded LDS
    #pragma unroll
    for (int cc = 0; cc < 4; ++cc) {
      int ch = tid + cc * 256;
      int row = ch >> 3, c8 = ch & 7;
      *(u16x8*)&As[row][c8 * 8] = cvt8(a0[cc], a1[cc]);
    }
    // B tile: 4 x 1KB async loads per wave
    #pragma unroll
    for (int i = 0; i < 4; ++i) {
      int brow = w * 32 + i * 8;
      const uint16_t* src =
          W + (size_t)(n0 + brow + (lane >> 3)) * NDM + k0 + (lane & 7) * 8;
      gload_lds16(src, &Bs[brow][0]);
    }
    __syncthreads();  // drains vmcnt (gload) + lgkm (ds_write)

    // T14: issue next K-step's A loads; MFMA below hides the latency
    if (k0 + 64 < NDM) {
      #pragma unroll
      for (int cc = 0; cc < 4; ++cc) {
        int ch = tid + cc * 256;
        int row = ch >> 3, c8 = ch & 7;
        const float* src = A + (size_t)(m0 + row) * NDM + (k0 + 64) + c8 * 8;
        a0[cc] = *(const float4*)src;
        a1[cc] = *(const float4*)(src + 4);
      }
    }

    #pragma unroll
    for (int kc = 0; kc < 2; ++kc) {
      bf16x8 af[4], bf[4];
      #pragma unroll
      for (int i = 0; i < 4; ++i) {
        af[i] = *(const bf16x8*)&As[wm * 64 + i * 16 + r16][kc * 32 + g * 8];
        bf[i] = *(const bf16x8*)&Bs[wn * 64 + i * 16 + r16][kc * 32 + g * 8];
      }
      #pragma unroll
      for (int mi = 0; mi < 4; ++mi)
        #pragma unroll
        for (int ni = 0; ni < 4; ++ni)
          acc[mi][ni] = __builtin_amdgcn_mfma_f32_16x16x32_bf16(
              af[mi], bf[ni], acc[mi][ni], 0, 0, 0);
    }
  }

  float scale = (z == 0) ? 0.125f * 1.44269504088896340736f : 1.0f;
  #pragma unroll
  for (int mi = 0; mi < 4; ++mi) {
    #pragma unroll
    for (int ni = 0; ni < 4; ++ni) {
      int m = m0 + wm * 64 + mi * 16 + g * 4;
      int n = n0 + wn * 64 + ni * 16 + r16;
      f32x4 a = acc[mi][ni];
      if (z == 2) {
        ushort4 pk;
        pk.x = f2bf(a[0]); pk.y = f2bf(a[1]);
        pk.z = f2bf(a[2]); pk.w = f2bf(a[3]);
        *(ushort4*)&XVT[(size_t)n * NTOK + m] = pk;  // transposed store
      } else {
        uint16_t* Y = (z == 0) ? XQ : XK;
        #pragma unroll
        for (int j = 0; j < 4; ++j)
          Y[(size_t)(m + j) * NDM + n] = f2bf(a[j] * scale);
      }
    }
  }
}

// ---------------------------------------------------------------------------
// Causal flash attention v4 — swapped QK^T, lane-local softmax.
// 1024 blocks, one item each: qc = 31-(bid>>5) (heavy first), bh = bid&31.
// Block = 4 waves x 16 q rows = 64 q rows; KVBLK = 64.
// QK^T computed as S^T = mfma(K_frag, Q_frag): C col = r16 = q, so each lane
// owns ONE q-row's kv values (16 of 64; groups g cover the rest).  Row-max =
// in-lane tree + 2 shfl_xor.  m,l are per-lane scalars.  T13 defer-rescale
// (THR=8); rescale redistributes sf to oacc rows via 4 shfls.  P packed to
// LDS as 4 x ds_write_b64.  PV unchanged (verified layout).
// ---------------------------------------------------------------------------
__global__ __launch_bounds__(256) void attn_kernel(
    const uint16_t* __restrict__ XQ, const uint16_t* __restrict__ XK,
    const uint16_t* __restrict__ XVT, uint16_t* __restrict__ AO) {
  __shared__ uint16_t Klds[64][72];   // [kv][d]
  __shared__ uint16_t Vlds[64][72];   // [d][kv]
  __shared__ uint16_t Plds[4][16][72];

  int tid = threadIdx.x;
  int lane = tid & 63;
  int w = tid >> 6;
  int g = lane >> 4, r16 = lane & 15;
  int srow = tid >> 2;          // staging: 0..63
  int scol = (tid & 3) * 16;    // 0,16,32,48

  int item = (int)blockIdx.x;
  int qc = 31 - (item >> 5);    // heavy chunks dispatch first
  int bh = item & 31;
  int b = bh >> 4, h = bh & 15;
  int q0 = qc * 64;
  int q0w = q0 + w * 16;
  int T = qc + 1;               // kv tiles of 64

  // Q fragments (B operand now; same per-lane data as A-operand layout)
  const uint16_t* qb =
      XQ + (size_t)(b * NS + q0w + r16) * NDM + h * NHD + g * 8;
  bf16x8 qf0 = *(const bf16x8*)qb;
  bf16x8 qf1 = *(const bf16x8*)(qb + 32);

  f32x4 oacc[4] = {};               // O[q=g*4+j][d=dt*16+r16]
  float mrow = -1e30f, lsum = 0.f;  // per-lane: q = r16

  const uint16_t* kbase = XK + (size_t)(b * NS + srow) * NDM + h * NHD + scol;
  const uint16_t* vbase = XVT + (size_t)(h * NHD + srow) * NTOK + b * NS + scol;

  u16x8 kr0 = *(const u16x8*)(kbase);
  u16x8 kr1 = *(const u16x8*)(kbase + 8);
  u16x8 vr0 = *(const u16x8*)(vbase);
  u16x8 vr1 = *(const u16x8*)(vbase + 8);

  for (int t = 0; t < T; ++t) {
    int kv0 = t * 64;
    __syncthreads();  // all waves done reading previous LDS tile
    *(u16x8*)&Klds[srow][scol]     = kr0;
    *(u16x8*)&Klds[srow][scol + 8] = kr1;
    *(u16x8*)&Vlds[srow][scol]     = vr0;
    *(u16x8*)&Vlds[srow][scol + 8] = vr1;
    __syncthreads();
    if (t + 1 < T) {  // prefetch next tile; compute hides latency
      const uint16_t* kp = kbase + (size_t)(t + 1) * 64 * NDM;
      const uint16_t* vp = vbase + (t + 1) * 64;
      kr0 = *(const u16x8*)(kp);
      kr1 = *(const u16x8*)(kp + 8);
      vr0 = *(const u16x8*)(vp);
      vr1 = *(const u16x8*)(vp + 8);
    }

    // ---- QK^T swapped: sc[t4] = S^T block; col=r16=q, row=g*4+j=kv_local ----
    f32x4 sc[4];
    __builtin_amdgcn_s_setprio(1);
    #pragma unroll
    for (int t4 = 0; t4 < 4; ++t4) {
      bf16x8 kf0 = *(const bf16x8*)&Klds[t4 * 16 + r16][g * 8];
      bf16x8 kf1 = *(const bf16x8*)&Klds[t4 * 16 + r16][32 + g * 8];
      f32x4 x = __builtin_amdgcn_mfma_f32_16x16x32_bf16(
          kf0, qf0, (f32x4){0.f, 0.f, 0.f, 0.f}, 0, 0, 0);
      x = __builtin_amdgcn_mfma_f32_16x16x32_bf16(kf1, qf1, x, 0, 0, 0);
      sc[t4] = x;
    }
    __builtin_amdgcn_s_setprio(0);

    // ---- causal mask (diag subtiles only; kv = kv0+t4*16+g*4+j, q = r16) ----
    #pragma unroll
    for (int t4 = 0; t4 < 4; ++t4) {
      if (kv0 + t4 * 16 + 15 > q0w) {  // wave-uniform guard
        #pragma unroll
        for (int j = 0; j < 4; ++j)
          if (kv0 + t4 * 16 + g * 4 + j > q0w + r16) sc[t4][j] = -1e30f;
      }
    }

    // ---- lane-local row max + cross-group combine ----
    float m16 = fmaxf(
        fmaxf(fmaxf(fmaxf(sc[0][0], sc[0][1]), fmaxf(sc[0][2], sc[0][3])),
              fmaxf(fmaxf(sc[1][0], sc[1][1]), fmaxf(sc[1][2], sc[1][3]))),
        fmaxf(fmaxf(fmaxf(sc[2][0], sc[2][1]), fmaxf(sc[2][2], sc[2][3])),
              fmaxf(fmaxf(sc[3][0], sc[3][1]), fmaxf(sc[3][2], sc[3][3]))));
    m16 = fmaxf(m16, __shfl_xor(m16, 16));
    m16 = fmaxf(m16, __shfl_xor(m16, 32));

    // ---- T13 defer-rescale (THR=8 in exp2 domain) ----
    if (!__all(m16 <= mrow + 8.0f)) {
      float mnew = fmaxf(mrow, m16);
      float sf = __builtin_amdgcn_exp2f(mrow - mnew);
      mrow = mnew;
      lsum *= sf;
      // oacc rows are q = g*4+j; fetch their sf from the owning lanes
      #pragma unroll
      for (int j = 0; j < 4; ++j) {
        float sfj = __shfl(sf, g * 4 + j);
        #pragma unroll
        for (int dt = 0; dt < 4; ++dt) oacc[dt][j] *= sfj;
      }
    }

    // ---- P = exp2(S - m), per-lane partial sum, pack to LDS ----
    #pragma unroll
    for (int t4 = 0; t4 < 4; ++t4) {
      float p0 = __builtin_amdgcn_exp2f(sc[t4][0] - mrow);
      float p1 = __builtin_amdgcn_exp2f(sc[t4][1] - mrow);
      float p2 = __builtin_amdgcn_exp2f(sc[t4][2] - mrow);
      float p3 = __builtin_amdgcn_exp2f(sc[t4][3] - mrow);
      lsum += (p0 + p1) + (p2 + p3);
      ushort4 pk;
      pk.x = f2bf(p0); pk.y = f2bf(p1); pk.z = f2bf(p2); pk.w = f2bf(p3);
      *(ushort4*)&Plds[w][r16][t4 * 16 + g * 4] = pk;
    }

    // ---- PV (unchanged verified layout) ----
    bf16x8 pa0 = *(const bf16x8*)&Plds[w][r16][g * 8];
    bf16x8 pa1 = *(const bf16x8*)&Plds[w][r16][32 + g * 8];
    __builtin_amdgcn_s_setprio(1);
    #pragma unroll
    for (int dt = 0; dt < 4; ++dt) {
      bf16x8 vf0 = *(const bf16x8*)&Vlds[dt * 16 + r16][g * 8];
      bf16x8 vf1 = *(const bf16x8*)&Vlds[dt * 16 + r16][32 + g * 8];
      oacc[dt] = __builtin_amdgcn_mfma_f32_16x16x32_bf16(pa0, vf0, oacc[dt], 0, 0, 0);
      oacc[dt] = __builtin_amdgcn_mfma_f32_16x16x32_bf16(pa1, vf1, oacc[dt], 0, 0, 0);
    }
    __builtin_amdgcn_s_setprio(0);
  }

  // ---- epilogue: cross-group l reduce, redistribute, normalize, store ----
  float l2 = lsum + __shfl_xor(lsum, 16);
  float ltot = l2 + __shfl_xor(l2, 32);
  #pragma unroll
  for (int j = 0; j < 4; ++j) {
    float lt = __shfl(ltot, g * 4 + j);
    float inv = 1.0f / lt;
    size_t ro = (size_t)(b * NS + q0 + w * 16 + g * 4 + j) * NDM + h * NHD;
    #pragma unroll
    for (int dt = 0; dt < 4; ++dt)
      AO[ro + dt * 16 + r16] = f2bf(oacc[dt][j] * inv);
  }
}

// ---------------------------------------------------------------------------
// Output projection: out = AO @ wo^T (fp32 out). Both operands bf16 via
// global_load_lds, linear LDS, BK=64 (m97 structure).
// ---------------------------------------------------------------------------
__global__ __launch_bounds__(256) void out_gemm(
    const uint16_t* __restrict__ AO, const uint16_t* __restrict__ wob,
    float* __restrict__ out) {
  __shared__ uint16_t As[128][64];
  __shared__ uint16_t Bs[128][64];
  int m0 = blockIdx.x * 128, n0 = blockIdx.y * 128;
  int tid = threadIdx.x;
  int lane = tid & 63, w = tid >> 6;
  int g = lane >> 4, r16 = lane & 15;
  int wm = w >> 1, wn = w & 1;

  f32x4 acc[4][4] = {};

  for (int k0 = 0; k0 < NDM; k0 += 64) {
    __syncthreads();
    #pragma unroll
    for (int i = 0; i < 4; ++i) {
      int row = w * 32 + i * 8;
      const uint16_t* asrc =
          AO + (size_t)(m0 + row + (lane >> 3)) * NDM + k0 + (lane & 7) * 8;
      gload_lds16(asrc, &As[row][0]);
      const uint16_t* bsrc =
          wob + (size_t)(n0 + row + (lane >> 3)) * NDM + k0 + (lane & 7) * 8;
      gload_lds16(bsrc, &Bs[row][0]);
    }
    __syncthreads();

    #pragma unroll
    for (int kc = 0; kc < 2; ++kc) {
      bf16x8 af[4], bf[4];
      #pragma unroll
      for (int i = 0; i < 4; ++i) {
        af[i] = *(const bf16x8*)&As[wm * 64 + i * 16 + r16][kc * 32 + g * 8];
        bf[i] = *(const bf16x8*)&Bs[wn * 64 + i * 16 + r16][kc * 32 + g * 8];
      }
      #pragma unroll
      for (int mi = 0; mi < 4; ++mi)
        #pragma unroll
        for (int ni = 0; ni < 4; ++ni)
          acc[mi][ni] = __builtin_amdgcn_mfma_f32_16x16x32_bf16(
              af[mi], bf[ni], acc[mi][ni], 0, 0, 0);
    }
  }

  #pragma unroll
  for (int mi = 0; mi < 4; ++mi) {
    #pragma unroll
    for (int ni = 0; ni < 4; ++ni) {
      int m = m0 + wm * 64 + mi * 16 + g * 4;
      int n = n0 + wn * 64 + ni * 16 + r16;
      #pragma unroll
      for (int j = 0; j < 4; ++j)
        out[(size_t)(m + j) * NDM + n] = acc[mi][ni][j];
    }
  }
}

extern "C" void kernel_launch(void* const* d_in, const int* in_sizes, int n_in,
                              void* d_out, int out_size, void* d_ws,
                              size_t ws_size, hipStream_t stream) {
  const float* q  = (const float*)d_in[0];
  const float* k  = (const float*)d_in[1];
  const float* v  = (const float*)d_in[2];
  const float* wq = (const float*)d_in[3];
  const float* wk = (const float*)d_in[4];
  const float* wv = (const float*)d_in[5];
  const float* wo = (const float*)d_in[6];

  uint16_t* XQ  = (uint16_t*)d_ws;                 // [NTOK][NDM] bf16
  uint16_t* XK  = XQ + (size_t)NTOK * NDM;         // [NTOK][NDM]
  uint16_t* XVT = XK + (size_t)NTOK * NDM;         // [NDM][NTOK]
  uint16_t* AO  = XVT + (size_t)NTOK * NDM;        // [NTOK][NDM]
  uint16_t* WQB = AO + (size_t)NTOK * NDM;         // [NDM][NDM] bf16 weights
  uint16_t* WKB = WQB + (size_t)NDM * NDM;
  uint16_t* WVB = WKB + (size_t)NDM * NDM;
  uint16_t* WOB = WVB + (size_t)NDM * NDM;
  // total ws use: 40 MiB

  cvt_w<<<dim3(NDM * NDM / (256 * 8), 4), 256, 0, stream>>>(
      wq, wk, wv, wo, WQB, WKB, WVB, WOB);
  proj_gemm<<<dim3(NTOK / 128, NDM / 128, 3), 256, 0, stream>>>(
      q, k, v, WQB, WKB, WVB, XQ, XK, XVT);
  attn_kernel<<<dim3(1024), 256, 0, stream>>>(XQ, XK, XVT, AO);
  out_gemm<<<dim3(NTOK / 128, NDM / 128), 256, 0, stream>>>(
      AO, WOB, (float*)d_out);
}

// Round 5
// 125.723 us; speedup vs baseline: 2.2065x; 1.0457x over previous
//
#include <hip/hip_runtime.h>
#include <hip/hip_bf16.h>
#include <stdint.h>

#define NB 2
#define NS 2048
#define NDM 1024
#define NH 16
#define NHD 64
#define NTOK (NB * NS)  // 4096

typedef __bf16 bf16x8 __attribute__((ext_vector_type(8)));
typedef float f32x4 __attribute__((ext_vector_type(4)));
typedef uint16_t u16x8 __attribute__((ext_vector_type(8)));

static __device__ __forceinline__ uint16_t f2bf(float f) {
  __bf16 b = (__bf16)f;  // RNE, lowers to v_cvt_pk_bf16_f32 when paired
  union { __bf16 b; uint16_t u; } x; x.b = b;
  return x.u;
}

static __device__ __forceinline__ u16x8 cvt8(float4 a, float4 b) {
  u16x8 v;
  v[0] = f2bf(a.x); v[1] = f2bf(a.y); v[2] = f2bf(a.z); v[3] = f2bf(a.w);
  v[4] = f2bf(b.x); v[5] = f2bf(b.y); v[6] = f2bf(b.z); v[7] = f2bf(b.w);
  return v;
}

// async global->LDS, 16B per lane, wave-linear LDS destination
static __device__ __forceinline__ void gload_lds16(const void* g, void* l) {
  __builtin_amdgcn_global_load_lds(
      (const __attribute__((address_space(1))) void*)g,
      (__attribute__((address_space(3))) void*)l, 16, 0, 0);
}

// ---------------------------------------------------------------------------
// Weight fp32 -> bf16 convert (wq,wk,wv,wo), 1M elems each.
// ---------------------------------------------------------------------------
__global__ __launch_bounds__(256) void cvt_w(
    const float* __restrict__ w0, const float* __restrict__ w1,
    const float* __restrict__ w2, const float* __restrict__ w3,
    uint16_t* __restrict__ o0, uint16_t* __restrict__ o1,
    uint16_t* __restrict__ o2, uint16_t* __restrict__ o3) {
  int y = blockIdx.y;
  const float* src = (y == 0) ? w0 : (y == 1) ? w1 : (y == 2) ? w2 : w3;
  uint16_t* dst = (y == 0) ? o0 : (y == 1) ? o1 : (y == 2) ? o2 : o3;
  int i = ((int)blockIdx.x * 256 + (int)threadIdx.x) * 8;
  float4 a = *(const float4*)(src + i);
  float4 b = *(const float4*)(src + i + 4);
  *(u16x8*)&dst[i] = cvt8(a, b);
}

// ---------------------------------------------------------------------------
// Projections: C[128x128] tile of X @ W^T.
// A = fp32 activation, T14 async-stage (regs one K-step ahead), padded LDS.
// B = bf16 weights via global_load_lds with BOTH-SIDES XOR swizzle (rule #21):
//   16B granule c of row r lives at physical granule c^(r&7); the global
//   source address is pre-swizzled per lane, LDS dest stays linear, and the
//   frag read XORs the granule index.  Kills the 16-way bank conflict
//   (128B row stride, 16 lanes same col-range -> same 4 banks).
// z=0: XQ scaled by 0.125*log2e ; z=1: XK ; z=2: XVT (transposed store).
// ---------------------------------------------------------------------------
__global__ __launch_bounds__(256) void proj_gemm(
    const float* __restrict__ q, const float* __restrict__ k,
    const float* __restrict__ v, const uint16_t* __restrict__ wqb,
    const uint16_t* __restrict__ wkb, const uint16_t* __restrict__ wvb,
    uint16_t* __restrict__ XQ, uint16_t* __restrict__ XK,
    uint16_t* __restrict__ XVT) {
  __shared__ uint16_t As[128][72];  // padded: conflict-free frag reads
  __shared__ uint16_t Bs[128][64];  // linear: global_load_lds target (swz src)
  int z = blockIdx.z;
  const float* A = (z == 0) ? q : (z == 1) ? k : v;
  const uint16_t* W = (z == 0) ? wqb : (z == 1) ? wkb : wvb;
  int m0 = blockIdx.x * 128, n0 = blockIdx.y * 128;
  int tid = threadIdx.x;
  int lane = tid & 63, w = tid >> 6;
  int g = lane >> 4, r16 = lane & 15;
  int wm = w >> 1, wn = w & 1;
  // pre-swizzled source column (elements) for gload_lds B staging
  int bce = ((lane & 7) ^ ((lane >> 3) & 7)) * 8;
  int brlane = lane >> 3;

  f32x4 acc[4][4] = {};
  float4 a0[4], a1[4];  // prefetched A chunks (one K-step ahead)

  // prologue: load A(k0=0)
  #pragma unroll
  for (int cc = 0; cc < 4; ++cc) {
    int ch = tid + cc * 256;
    int row = ch >> 3, c8 = ch & 7;
    const float* src = A + (size_t)(m0 + row) * NDM + c8 * 8;
    a0[cc] = *(const float4*)src;
    a1[cc] = *(const float4*)(src + 4);
  }

  for (int k0 = 0; k0 < NDM; k0 += 64) {
    __syncthreads();  // prior readers done
    // A tile: cvt prefetched regs -> padded LDS
    #pragma unroll
    for (int cc = 0; cc < 4; ++cc) {
      int ch = tid + cc * 256;
      int row = ch >> 3, c8 = ch & 7;
      *(u16x8*)&As[row][c8 * 8] = cvt8(a0[cc], a1[cc]);
    }
    // B tile: 4 x 1KB async loads per wave, pre-swizzled global source
    #pragma unroll
    for (int i = 0; i < 4; ++i) {
      int brow = w * 32 + i * 8;
      const uint16_t* src =
          W + (size_t)(n0 + brow + brlane) * NDM + k0 + bce;
      gload_lds16(src, &Bs[brow][0]);
    }
    __syncthreads();  // drains vmcnt (gload) + lgkm (ds_write)

    // T14: issue next K-step's A loads; MFMA below hides the latency
    if (k0 + 64 < NDM) {
      #pragma unroll
      for (int cc = 0; cc < 4; ++cc) {
        int ch = tid + cc * 256;
        int row = ch >> 3, c8 = ch & 7;
        const float* src = A + (size_t)(m0 + row) * NDM + (k0 + 64) + c8 * 8;
        a0[cc] = *(const float4*)src;
        a1[cc] = *(const float4*)(src + 4);
      }
    }

    #pragma unroll
    for (int kc = 0; kc < 2; ++kc) {
      bf16x8 af[4], bf[4];
      #pragma unroll
      for (int i = 0; i < 4; ++i) {
        af[i] = *(const bf16x8*)&As[wm * 64 + i * 16 + r16][kc * 32 + g * 8];
        int gran = (kc * 4 + g) ^ (r16 & 7);  // read-side XOR (matches src)
        bf[i] = *(const bf16x8*)&Bs[wn * 64 + i * 16 + r16][gran * 8];
      }
      #pragma unroll
      for (int mi = 0; mi < 4; ++mi)
        #pragma unroll
        for (int ni = 0; ni < 4; ++ni)
          acc[mi][ni] = __builtin_amdgcn_mfma_f32_16x16x32_bf16(
              af[mi], bf[ni], acc[mi][ni], 0, 0, 0);
    }
  }

  float scale = (z == 0) ? 0.125f * 1.44269504088896340736f : 1.0f;
  #pragma unroll
  for (int mi = 0; mi < 4; ++mi) {
    #pragma unroll
    for (int ni = 0; ni < 4; ++ni) {
      int m = m0 + wm * 64 + mi * 16 + g * 4;
      int n = n0 + wn * 64 + ni * 16 + r16;
      f32x4 a = acc[mi][ni];
      if (z == 2) {
        ushort4 pk;
        pk.x = f2bf(a[0]); pk.y = f2bf(a[1]);
        pk.z = f2bf(a[2]); pk.w = f2bf(a[3]);
        *(ushort4*)&XVT[(size_t)n * NTOK + m] = pk;  // transposed store
      } else {
        uint16_t* Y = (z == 0) ? XQ : XK;
        #pragma unroll
        for (int j = 0; j < 4; ++j)
          Y[(size_t)(m + j) * NDM + n] = f2bf(a[j] * scale);
      }
    }
  }
}

// ---------------------------------------------------------------------------
// Causal flash attention v4 — swapped QK^T, lane-local softmax (unchanged).
// ---------------------------------------------------------------------------
__global__ __launch_bounds__(256) void attn_kernel(
    const uint16_t* __restrict__ XQ, const uint16_t* __restrict__ XK,
    const uint16_t* __restrict__ XVT, uint16_t* __restrict__ AO) {
  __shared__ uint16_t Klds[64][72];   // [kv][d]
  __shared__ uint16_t Vlds[64][72];   // [d][kv]
  __shared__ uint16_t Plds[4][16][72];

  int tid = threadIdx.x;
  int lane = tid & 63;
  int w = tid >> 6;
  int g = lane >> 4, r16 = lane & 15;
  int srow = tid >> 2;          // staging: 0..63
  int scol = (tid & 3) * 16;    // 0,16,32,48

  int item = (int)blockIdx.x;
  int qc = 31 - (item >> 5);    // heavy chunks dispatch first
  int bh = item & 31;
  int b = bh >> 4, h = bh & 15;
  int q0 = qc * 64;
  int q0w = q0 + w * 16;
  int T = qc + 1;               // kv tiles of 64

  const uint16_t* qb =
      XQ + (size_t)(b * NS + q0w + r16) * NDM + h * NHD + g * 8;
  bf16x8 qf0 = *(const bf16x8*)qb;
  bf16x8 qf1 = *(const bf16x8*)(qb + 32);

  f32x4 oacc[4] = {};               // O[q=g*4+j][d=dt*16+r16]
  float mrow = -1e30f, lsum = 0.f;  // per-lane: q = r16

  const uint16_t* kbase = XK + (size_t)(b * NS + srow) * NDM + h * NHD + scol;
  const uint16_t* vbase = XVT + (size_t)(h * NHD + srow) * NTOK + b * NS + scol;

  u16x8 kr0 = *(const u16x8*)(kbase);
  u16x8 kr1 = *(const u16x8*)(kbase + 8);
  u16x8 vr0 = *(const u16x8*)(vbase);
  u16x8 vr1 = *(const u16x8*)(vbase + 8);

  for (int t = 0; t < T; ++t) {
    int kv0 = t * 64;
    __syncthreads();  // all waves done reading previous LDS tile
    *(u16x8*)&Klds[srow][scol]     = kr0;
    *(u16x8*)&Klds[srow][scol + 8] = kr1;
    *(u16x8*)&Vlds[srow][scol]     = vr0;
    *(u16x8*)&Vlds[srow][scol + 8] = vr1;
    __syncthreads();
    if (t + 1 < T) {  // prefetch next tile; compute hides latency
      const uint16_t* kp = kbase + (size_t)(t + 1) * 64 * NDM;
      const uint16_t* vp = vbase + (t + 1) * 64;
      kr0 = *(const u16x8*)(kp);
      kr1 = *(const u16x8*)(kp + 8);
      vr0 = *(const u16x8*)(vp);
      vr1 = *(const u16x8*)(vp + 8);
    }

    // ---- QK^T swapped: col=r16=q, row=g*4+j=kv_local ----
    f32x4 sc[4];
    __builtin_amdgcn_s_setprio(1);
    #pragma unroll
    for (int t4 = 0; t4 < 4; ++t4) {
      bf16x8 kf0 = *(const bf16x8*)&Klds[t4 * 16 + r16][g * 8];
      bf16x8 kf1 = *(const bf16x8*)&Klds[t4 * 16 + r16][32 + g * 8];
      f32x4 x = __builtin_amdgcn_mfma_f32_16x16x32_bf16(
          kf0, qf0, (f32x4){0.f, 0.f, 0.f, 0.f}, 0, 0, 0);
      x = __builtin_amdgcn_mfma_f32_16x16x32_bf16(kf1, qf1, x, 0, 0, 0);
      sc[t4] = x;
    }
    __builtin_amdgcn_s_setprio(0);

    // ---- causal mask (diag subtiles only; kv = kv0+t4*16+g*4+j, q = r16) ----
    #pragma unroll
    for (int t4 = 0; t4 < 4; ++t4) {
      if (kv0 + t4 * 16 + 15 > q0w) {  // wave-uniform guard
        #pragma unroll
        for (int j = 0; j < 4; ++j)
          if (kv0 + t4 * 16 + g * 4 + j > q0w + r16) sc[t4][j] = -1e30f;
      }
    }

    // ---- lane-local row max + cross-group combine ----
    float m16 = fmaxf(
        fmaxf(fmaxf(fmaxf(sc[0][0], sc[0][1]), fmaxf(sc[0][2], sc[0][3])),
              fmaxf(fmaxf(sc[1][0], sc[1][1]), fmaxf(sc[1][2], sc[1][3]))),
        fmaxf(fmaxf(fmaxf(sc[2][0], sc[2][1]), fmaxf(sc[2][2], sc[2][3])),
              fmaxf(fmaxf(sc[3][0], sc[3][1]), fmaxf(sc[3][2], sc[3][3]))));
    m16 = fmaxf(m16, __shfl_xor(m16, 16));
    m16 = fmaxf(m16, __shfl_xor(m16, 32));

    // ---- T13 defer-rescale (THR=8 in exp2 domain) ----
    if (!__all(m16 <= mrow + 8.0f)) {
      float mnew = fmaxf(mrow, m16);
      float sf = __builtin_amdgcn_exp2f(mrow - mnew);
      mrow = mnew;
      lsum *= sf;
      #pragma unroll
      for (int j = 0; j < 4; ++j) {
        float sfj = __shfl(sf, g * 4 + j);
        #pragma unroll
        for (int dt = 0; dt < 4; ++dt) oacc[dt][j] *= sfj;
      }
    }

    // ---- P = exp2(S - m), per-lane partial sum, pack to LDS ----
    #pragma unroll
    for (int t4 = 0; t4 < 4; ++t4) {
      float p0 = __builtin_amdgcn_exp2f(sc[t4][0] - mrow);
      float p1 = __builtin_amdgcn_exp2f(sc[t4][1] - mrow);
      float p2 = __builtin_amdgcn_exp2f(sc[t4][2] - mrow);
      float p3 = __builtin_amdgcn_exp2f(sc[t4][3] - mrow);
      lsum += (p0 + p1) + (p2 + p3);
      ushort4 pk;
      pk.x = f2bf(p0); pk.y = f2bf(p1); pk.z = f2bf(p2); pk.w = f2bf(p3);
      *(ushort4*)&Plds[w][r16][t4 * 16 + g * 4] = pk;
    }

    // ---- PV ----
    bf16x8 pa0 = *(const bf16x8*)&Plds[w][r16][g * 8];
    bf16x8 pa1 = *(const bf16x8*)&Plds[w][r16][32 + g * 8];
    __builtin_amdgcn_s_setprio(1);
    #pragma unroll
    for (int dt = 0; dt < 4; ++dt) {
      bf16x8 vf0 = *(const bf16x8*)&Vlds[dt * 16 + r16][g * 8];
      bf16x8 vf1 = *(const bf16x8*)&Vlds[dt * 16 + r16][32 + g * 8];
      oacc[dt] = __builtin_amdgcn_mfma_f32_16x16x32_bf16(pa0, vf0, oacc[dt], 0, 0, 0);
      oacc[dt] = __builtin_amdgcn_mfma_f32_16x16x32_bf16(pa1, vf1, oacc[dt], 0, 0, 0);
    }
    __builtin_amdgcn_s_setprio(0);
  }

  // ---- epilogue: cross-group l reduce, redistribute, normalize, store ----
  float l2 = lsum + __shfl_xor(lsum, 16);
  float ltot = l2 + __shfl_xor(l2, 32);
  #pragma unroll
  for (int j = 0; j < 4; ++j) {
    float lt = __shfl(ltot, g * 4 + j);
    float inv = 1.0f / lt;
    size_t ro = (size_t)(b * NS + q0 + w * 16 + g * 4 + j) * NDM + h * NHD;
    #pragma unroll
    for (int dt = 0; dt < 4; ++dt)
      AO[ro + dt * 16 + r16] = f2bf(oacc[dt][j] * inv);
  }
}

// ---------------------------------------------------------------------------
// Output projection: out = AO @ wo^T (fp32 out). Both operands bf16 via
// global_load_lds with both-sides XOR swizzle (same as proj B tile).
// ---------------------------------------------------------------------------
__global__ __launch_bounds__(256) void out_gemm(
    const uint16_t* __restrict__ AO, const uint16_t* __restrict__ wob,
    float* __restrict__ out) {
  __shared__ uint16_t As[128][64];
  __shared__ uint16_t Bs[128][64];
  int m0 = blockIdx.x * 128, n0 = blockIdx.y * 128;
  int tid = threadIdx.x;
  int lane = tid & 63, w = tid >> 6;
  int g = lane >> 4, r16 = lane & 15;
  int wm = w >> 1, wn = w & 1;
  int bce = ((lane & 7) ^ ((lane >> 3) & 7)) * 8;  // pre-swizzled src col
  int brlane = lane >> 3;

  f32x4 acc[4][4] = {};

  for (int k0 = 0; k0 < NDM; k0 += 64) {
    __syncthreads();
    #pragma unroll
    for (int i = 0; i < 4; ++i) {
      int row = w * 32 + i * 8;
      const uint16_t* asrc =
          AO + (size_t)(m0 + row + brlane) * NDM + k0 + bce;
      gload_lds16(asrc, &As[row][0]);
      const uint16_t* bsrc =
          wob + (size_t)(n0 + row + brlane) * NDM + k0 + bce;
      gload_lds16(bsrc, &Bs[row][0]);
    }
    __syncthreads();

    #pragma unroll
    for (int kc = 0; kc < 2; ++kc) {
      bf16x8 af[4], bf[4];
      #pragma unroll
      for (int i = 0; i < 4; ++i) {
        int gran = (kc * 4 + g) ^ (r16 & 7);
        af[i] = *(const bf16x8*)&As[wm * 64 + i * 16 + r16][gran * 8];
        bf[i] = *(const bf16x8*)&Bs[wn * 64 + i * 16 + r16][gran * 8];
      }
      #pragma unroll
      for (int mi = 0; mi < 4; ++mi)
        #pragma unroll
        for (int ni = 0; ni < 4; ++ni)
          acc[mi][ni] = __builtin_amdgcn_mfma_f32_16x16x32_bf16(
              af[mi], bf[ni], acc[mi][ni], 0, 0, 0);
    }
  }

  #pragma unroll
  for (int mi = 0; mi < 4; ++mi) {
    #pragma unroll
    for (int ni = 0; ni < 4; ++ni) {
      int m = m0 + wm * 64 + mi * 16 + g * 4;
      int n = n0 + wn * 64 + ni * 16 + r16;
      #pragma unroll
      for (int j = 0; j < 4; ++j)
        out[(size_t)(m + j) * NDM + n] = acc[mi][ni][j];
    }
  }
}

extern "C" void kernel_launch(void* const* d_in, const int* in_sizes, int n_in,
                              void* d_out, int out_size, void* d_ws,
                              size_t ws_size, hipStream_t stream) {
  const float* q  = (const float*)d_in[0];
  const float* k  = (const float*)d_in[1];
  const float* v  = (const float*)d_in[2];
  const float* wq = (const float*)d_in[3];
  const float* wk = (const float*)d_in[4];
  const float* wv = (const float*)d_in[5];
  const float* wo = (const float*)d_in[6];

  uint16_t* XQ  = (uint16_t*)d_ws;                 // [NTOK][NDM] bf16
  uint16_t* XK  = XQ + (size_t)NTOK * NDM;         // [NTOK][NDM]
  uint16_t* XVT = XK + (size_t)NTOK * NDM;         // [NDM][NTOK]
  uint16_t* AO  = XVT + (size_t)NTOK * NDM;        // [NTOK][NDM]
  uint16_t* WQB = AO + (size_t)NTOK * NDM;         // [NDM][NDM] bf16 weights
  uint16_t* WKB = WQB + (size_t)NDM * NDM;
  uint16_t* WVB = WKB + (size_t)NDM * NDM;
  uint16_t* WOB = WVB + (size_t)NDM * NDM;
  // total ws use: 40 MiB

  cvt_w<<<dim3(NDM * NDM / (256 * 8), 4), 256, 0, stream>>>(
      wq, wk, wv, wo, WQB, WKB, WVB, WOB);
  proj_gemm<<<dim3(NTOK / 128, NDM / 128, 3), 256, 0, stream>>>(
      q, k, v, WQB, WKB, WVB, XQ, XK, XVT);
  attn_kernel<<<dim3(1024), 256, 0, stream>>>(XQ, XK, XVT, AO);
  out_gemm<<<dim3(NTOK / 128, NDM / 128), 256, 0, stream>>>(
      AO, WOB, (float*)d_out);
}

// Round 6
// 120.146 us; speedup vs baseline: 2.3090x; 1.0464x over previous
//
#include <hip/hip_runtime.h>
#include <hip/hip_bf16.h>
#include <stdint.h>

#define NB 2
#define NS 2048
#define NDM 1024
#define NH 16
#define NHD 64
#define NTOK (NB * NS)  // 4096

typedef __bf16 bf16x8 __attribute__((ext_vector_type(8)));
typedef float f32x4 __attribute__((ext_vector_type(4)));
typedef uint16_t u16x8 __attribute__((ext_vector_type(8)));

static __device__ __forceinline__ uint16_t f2bf(float f) {
  __bf16 b = (__bf16)f;  // RNE, lowers to v_cvt_pk_bf16_f32 when paired
  union { __bf16 b; uint16_t u; } x; x.b = b;
  return x.u;
}

static __device__ __forceinline__ u16x8 cvt8(float4 a, float4 b) {
  u16x8 v;
  v[0] = f2bf(a.x); v[1] = f2bf(a.y); v[2] = f2bf(a.z); v[3] = f2bf(a.w);
  v[4] = f2bf(b.x); v[5] = f2bf(b.y); v[6] = f2bf(b.z); v[7] = f2bf(b.w);
  return v;
}

// async global->LDS, 16B per lane, wave-linear LDS destination
static __device__ __forceinline__ void gload_lds16(const void* g, void* l) {
  __builtin_amdgcn_global_load_lds(
      (const __attribute__((address_space(1))) void*)g,
      (__attribute__((address_space(3))) void*)l, 16, 0, 0);
}

// ---------------------------------------------------------------------------
// Weight fp32 -> bf16 convert (wq,wk,wv,wo), 1M elems each.
// ---------------------------------------------------------------------------
__global__ __launch_bounds__(256) void cvt_w(
    const float* __restrict__ w0, const float* __restrict__ w1,
    const float* __restrict__ w2, const float* __restrict__ w3,
    uint16_t* __restrict__ o0, uint16_t* __restrict__ o1,
    uint16_t* __restrict__ o2, uint16_t* __restrict__ o3) {
  int y = blockIdx.y;
  const float* src = (y == 0) ? w0 : (y == 1) ? w1 : (y == 2) ? w2 : w3;
  uint16_t* dst = (y == 0) ? o0 : (y == 1) ? o1 : (y == 2) ? o2 : o3;
  int i = ((int)blockIdx.x * 256 + (int)threadIdx.x) * 8;
  float4 a = *(const float4*)(src + i);
  float4 b = *(const float4*)(src + i + 4);
  *(u16x8*)&dst[i] = cvt8(a, b);
}

// ---------------------------------------------------------------------------
// Projections: C[128x128] tile of X @ W^T — T3-minimum pipelined.
// Double-buffered LDS; tile t+1's staging (gload_lds B + cvt/ds_write A) is
// issued BEFORE tile t's ds_read+MFMA, so the single per-step __syncthreads
// (vmcnt(0) drain) finds loads already complete.  One barrier per K-step.
// Both tiles use the both-sides XOR granule swizzle (granule c of row r at
// physical c^(r&7)): B via pre-swizzled global source for the linear
// gload_lds dest; A via swizzled ds_write (reg-staged).  Frag reads XOR the
// granule -> 2-way conflicts only.
// z=0: XQ scaled by 0.125*log2e ; z=1: XK ; z=2: XVT (transposed store).
// ---------------------------------------------------------------------------
__global__ __launch_bounds__(256) void proj_gemm(
    const float* __restrict__ q, const float* __restrict__ k,
    const float* __restrict__ v, const uint16_t* __restrict__ wqb,
    const uint16_t* __restrict__ wkb, const uint16_t* __restrict__ wvb,
    uint16_t* __restrict__ XQ, uint16_t* __restrict__ XK,
    uint16_t* __restrict__ XVT) {
  __shared__ uint16_t As[2][128][64];
  __shared__ uint16_t Bs[2][128][64];
  int z = blockIdx.z;
  const float* A = (z == 0) ? q : (z == 1) ? k : v;
  const uint16_t* W = (z == 0) ? wqb : (z == 1) ? wkb : wvb;
  int m0 = blockIdx.x * 128, n0 = blockIdx.y * 128;
  int tid = threadIdx.x;
  int lane = tid & 63, w = tid >> 6;
  int g = lane >> 4, r16 = lane & 15;
  int wm = w >> 1, wn = w & 1;
  // pre-swizzled source column (elements) for gload_lds B staging
  int bce = ((lane & 7) ^ ((lane >> 3) & 7)) * 8;
  int brlane = lane >> 3;

  f32x4 acc[4][4] = {};
  float4 a0[4], a1[4];  // A fp32 regs, one K-step ahead of the ds_write

  // ---- prologue ----
  #pragma unroll
  for (int cc = 0; cc < 4; ++cc) {  // A(k=0) -> regs
    int ch = tid + cc * 256;
    int row = ch >> 3, c8 = ch & 7;
    const float* src = A + (size_t)(m0 + row) * NDM + c8 * 8;
    a0[cc] = *(const float4*)src;
    a1[cc] = *(const float4*)(src + 4);
  }
  #pragma unroll
  for (int i = 0; i < 4; ++i) {  // B(k=0) -> Bs[0]
    int brow = w * 32 + i * 8;
    gload_lds16(W + (size_t)(n0 + brow + brlane) * NDM + bce, &Bs[0][brow][0]);
  }
  #pragma unroll
  for (int cc = 0; cc < 4; ++cc) {  // A(k=0) -> As[0] (swizzled ds_write)
    int ch = tid + cc * 256;
    int row = ch >> 3, c8 = ch & 7;
    *(u16x8*)&As[0][row][((c8 ^ (row & 7)) * 8)] = cvt8(a0[cc], a1[cc]);
  }
  #pragma unroll
  for (int cc = 0; cc < 4; ++cc) {  // A(k=64) -> regs
    int ch = tid + cc * 256;
    int row = ch >> 3, c8 = ch & 7;
    const float* src = A + (size_t)(m0 + row) * NDM + 64 + c8 * 8;
    a0[cc] = *(const float4*)src;
    a1[cc] = *(const float4*)(src + 4);
  }
  __syncthreads();

  // ---- main loop: 16 K-steps, 1 barrier each ----
  for (int t = 0; t < 16; ++t) {
    int cur = t & 1, nxt = cur ^ 1;
    if (t < 15) {  // stage tile t+1 into the other buffer (issued early)
      int k1 = (t + 1) * 64;
      #pragma unroll
      for (int i = 0; i < 4; ++i) {
        int brow = w * 32 + i * 8;
        gload_lds16(W + (size_t)(n0 + brow + brlane) * NDM + k1 + bce,
                    &Bs[nxt][brow][0]);
      }
      #pragma unroll
      for (int cc = 0; cc < 4; ++cc) {
        int ch = tid + cc * 256;
        int row = ch >> 3, c8 = ch & 7;
        *(u16x8*)&As[nxt][row][((c8 ^ (row & 7)) * 8)] = cvt8(a0[cc], a1[cc]);
      }
      if (t < 14) {  // refill A regs for tile t+2
        int k2 = (t + 2) * 64;
        #pragma unroll
        for (int cc = 0; cc < 4; ++cc) {
          int ch = tid + cc * 256;
          int row = ch >> 3, c8 = ch & 7;
          const float* src = A + (size_t)(m0 + row) * NDM + k2 + c8 * 8;
          a0[cc] = *(const float4*)src;
          a1[cc] = *(const float4*)(src + 4);
        }
      }
    }

    // compute on buf[cur] while the staging loads fly
    #pragma unroll
    for (int kc = 0; kc < 2; ++kc) {
      bf16x8 af[4], bf[4];
      #pragma unroll
      for (int i = 0; i < 4; ++i) {
        int gran = (kc * 4 + g) ^ (r16 & 7);
        af[i] = *(const bf16x8*)&As[cur][wm * 64 + i * 16 + r16][gran * 8];
        bf[i] = *(const bf16x8*)&Bs[cur][wn * 64 + i * 16 + r16][gran * 8];
      }
      #pragma unroll
      for (int mi = 0; mi < 4; ++mi)
        #pragma unroll
        for (int ni = 0; ni < 4; ++ni)
          acc[mi][ni] = __builtin_amdgcn_mfma_f32_16x16x32_bf16(
              af[mi], bf[ni], acc[mi][ni], 0, 0, 0);
    }
    __syncthreads();  // drains staging; buf[nxt] ready for t+1
  }

  float scale = (z == 0) ? 0.125f * 1.44269504088896340736f : 1.0f;
  #pragma unroll
  for (int mi = 0; mi < 4; ++mi) {
    #pragma unroll
    for (int ni = 0; ni < 4; ++ni) {
      int m = m0 + wm * 64 + mi * 16 + g * 4;
      int n = n0 + wn * 64 + ni * 16 + r16;
      f32x4 a = acc[mi][ni];
      if (z == 2) {
        ushort4 pk;
        pk.x = f2bf(a[0]); pk.y = f2bf(a[1]);
        pk.z = f2bf(a[2]); pk.w = f2bf(a[3]);
        *(ushort4*)&XVT[(size_t)n * NTOK + m] = pk;  // transposed store
      } else {
        uint16_t* Y = (z == 0) ? XQ : XK;
        #pragma unroll
        for (int j = 0; j < 4; ++j)
          Y[(size_t)(m + j) * NDM + n] = f2bf(a[j] * scale);
      }
    }
  }
}

// ---------------------------------------------------------------------------
// Causal flash attention v4 — swapped QK^T, lane-local softmax (unchanged).
// ---------------------------------------------------------------------------
__global__ __launch_bounds__(256) void attn_kernel(
    const uint16_t* __restrict__ XQ, const uint16_t* __restrict__ XK,
    const uint16_t* __restrict__ XVT, uint16_t* __restrict__ AO) {
  __shared__ uint16_t Klds[64][72];   // [kv][d]
  __shared__ uint16_t Vlds[64][72];   // [d][kv]
  __shared__ uint16_t Plds[4][16][72];

  int tid = threadIdx.x;
  int lane = tid & 63;
  int w = tid >> 6;
  int g = lane >> 4, r16 = lane & 15;
  int srow = tid >> 2;          // staging: 0..63
  int scol = (tid & 3) * 16;    // 0,16,32,48

  int item = (int)blockIdx.x;
  int qc = 31 - (item >> 5);    // heavy chunks dispatch first
  int bh = item & 31;
  int b = bh >> 4, h = bh & 15;
  int q0 = qc * 64;
  int q0w = q0 + w * 16;
  int T = qc + 1;               // kv tiles of 64

  const uint16_t* qb =
      XQ + (size_t)(b * NS + q0w + r16) * NDM + h * NHD + g * 8;
  bf16x8 qf0 = *(const bf16x8*)qb;
  bf16x8 qf1 = *(const bf16x8*)(qb + 32);

  f32x4 oacc[4] = {};               // O[q=g*4+j][d=dt*16+r16]
  float mrow = -1e30f, lsum = 0.f;  // per-lane: q = r16

  const uint16_t* kbase = XK + (size_t)(b * NS + srow) * NDM + h * NHD + scol;
  const uint16_t* vbase = XVT + (size_t)(h * NHD + srow) * NTOK + b * NS + scol;

  u16x8 kr0 = *(const u16x8*)(kbase);
  u16x8 kr1 = *(const u16x8*)(kbase + 8);
  u16x8 vr0 = *(const u16x8*)(vbase);
  u16x8 vr1 = *(const u16x8*)(vbase + 8);

  for (int t = 0; t < T; ++t) {
    int kv0 = t * 64;
    __syncthreads();  // all waves done reading previous LDS tile
    *(u16x8*)&Klds[srow][scol]     = kr0;
    *(u16x8*)&Klds[srow][scol + 8] = kr1;
    *(u16x8*)&Vlds[srow][scol]     = vr0;
    *(u16x8*)&Vlds[srow][scol + 8] = vr1;
    __syncthreads();
    if (t + 1 < T) {  // prefetch next tile; compute hides latency
      const uint16_t* kp = kbase + (size_t)(t + 1) * 64 * NDM;
      const uint16_t* vp = vbase + (t + 1) * 64;
      kr0 = *(const u16x8*)(kp);
      kr1 = *(const u16x8*)(kp + 8);
      vr0 = *(const u16x8*)(vp);
      vr1 = *(const u16x8*)(vp + 8);
    }

    // ---- QK^T swapped: col=r16=q, row=g*4+j=kv_local ----
    f32x4 sc[4];
    __builtin_amdgcn_s_setprio(1);
    #pragma unroll
    for (int t4 = 0; t4 < 4; ++t4) {
      bf16x8 kf0 = *(const bf16x8*)&Klds[t4 * 16 + r16][g * 8];
      bf16x8 kf1 = *(const bf16x8*)&Klds[t4 * 16 + r16][32 + g * 8];
      f32x4 x = __builtin_amdgcn_mfma_f32_16x16x32_bf16(
          kf0, qf0, (f32x4){0.f, 0.f, 0.f, 0.f}, 0, 0, 0);
      x = __builtin_amdgcn_mfma_f32_16x16x32_bf16(kf1, qf1, x, 0, 0, 0);
      sc[t4] = x;
    }
    __builtin_amdgcn_s_setprio(0);

    // ---- causal mask (diag subtiles only; kv = kv0+t4*16+g*4+j, q = r16) ----
    #pragma unroll
    for (int t4 = 0; t4 < 4; ++t4) {
      if (kv0 + t4 * 16 + 15 > q0w) {  // wave-uniform guard
        #pragma unroll
        for (int j = 0; j < 4; ++j)
          if (kv0 + t4 * 16 + g * 4 + j > q0w + r16) sc[t4][j] = -1e30f;
      }
    }

    // ---- lane-local row max + cross-group combine ----
    float m16 = fmaxf(
        fmaxf(fmaxf(fmaxf(sc[0][0], sc[0][1]), fmaxf(sc[0][2], sc[0][3])),
              fmaxf(fmaxf(sc[1][0], sc[1][1]), fmaxf(sc[1][2], sc[1][3]))),
        fmaxf(fmaxf(fmaxf(sc[2][0], sc[2][1]), fmaxf(sc[2][2], sc[2][3])),
              fmaxf(fmaxf(sc[3][0], sc[3][1]), fmaxf(sc[3][2], sc[3][3]))));
    m16 = fmaxf(m16, __shfl_xor(m16, 16));
    m16 = fmaxf(m16, __shfl_xor(m16, 32));

    // ---- T13 defer-rescale (THR=8 in exp2 domain) ----
    if (!__all(m16 <= mrow + 8.0f)) {
      float mnew = fmaxf(mrow, m16);
      float sf = __builtin_amdgcn_exp2f(mrow - mnew);
      mrow = mnew;
      lsum *= sf;
      #pragma unroll
      for (int j = 0; j < 4; ++j) {
        float sfj = __shfl(sf, g * 4 + j);
        #pragma unroll
        for (int dt = 0; dt < 4; ++dt) oacc[dt][j] *= sfj;
      }
    }

    // ---- P = exp2(S - m), per-lane partial sum, pack to LDS ----
    #pragma unroll
    for (int t4 = 0; t4 < 4; ++t4) {
      float p0 = __builtin_amdgcn_exp2f(sc[t4][0] - mrow);
      float p1 = __builtin_amdgcn_exp2f(sc[t4][1] - mrow);
      float p2 = __builtin_amdgcn_exp2f(sc[t4][2] - mrow);
      float p3 = __builtin_amdgcn_exp2f(sc[t4][3] - mrow);
      lsum += (p0 + p1) + (p2 + p3);
      ushort4 pk;
      pk.x = f2bf(p0); pk.y = f2bf(p1); pk.z = f2bf(p2); pk.w = f2bf(p3);
      *(ushort4*)&Plds[w][r16][t4 * 16 + g * 4] = pk;
    }

    // ---- PV ----
    bf16x8 pa0 = *(const bf16x8*)&Plds[w][r16][g * 8];
    bf16x8 pa1 = *(const bf16x8*)&Plds[w][r16][32 + g * 8];
    __builtin_amdgcn_s_setprio(1);
    #pragma unroll
    for (int dt = 0; dt < 4; ++dt) {
      bf16x8 vf0 = *(const bf16x8*)&Vlds[dt * 16 + r16][g * 8];
      bf16x8 vf1 = *(const bf16x8*)&Vlds[dt * 16 + r16][32 + g * 8];
      oacc[dt] = __builtin_amdgcn_mfma_f32_16x16x32_bf16(pa0, vf0, oacc[dt], 0, 0, 0);
      oacc[dt] = __builtin_amdgcn_mfma_f32_16x16x32_bf16(pa1, vf1, oacc[dt], 0, 0, 0);
    }
    __builtin_amdgcn_s_setprio(0);
  }

  // ---- epilogue: cross-group l reduce, redistribute, normalize, store ----
  float l2 = lsum + __shfl_xor(lsum, 16);
  float ltot = l2 + __shfl_xor(l2, 32);
  #pragma unroll
  for (int j = 0; j < 4; ++j) {
    float lt = __shfl(ltot, g * 4 + j);
    float inv = 1.0f / lt;
    size_t ro = (size_t)(b * NS + q0 + w * 16 + g * 4 + j) * NDM + h * NHD;
    #pragma unroll
    for (int dt = 0; dt < 4; ++dt)
      AO[ro + dt * 16 + r16] = f2bf(oacc[dt][j] * inv);
  }
}

// ---------------------------------------------------------------------------
// Output projection: out = AO @ wo^T (fp32 out) — same T3-minimum pipeline,
// both operands bf16 via gload_lds with pre-swizzled sources, dbuf LDS,
// one barrier per K-step.
// ---------------------------------------------------------------------------
__global__ __launch_bounds__(256) void out_gemm(
    const uint16_t* __restrict__ AO, const uint16_t* __restrict__ wob,
    float* __restrict__ out) {
  __shared__ uint16_t As[2][128][64];
  __shared__ uint16_t Bs[2][128][64];
  int m0 = blockIdx.x * 128, n0 = blockIdx.y * 128;
  int tid = threadIdx.x;
  int lane = tid & 63, w = tid >> 6;
  int g = lane >> 4, r16 = lane & 15;
  int wm = w >> 1, wn = w & 1;
  int bce = ((lane & 7) ^ ((lane >> 3) & 7)) * 8;  // pre-swizzled src col
  int brlane = lane >> 3;

  f32x4 acc[4][4] = {};

  // prologue: stage tile 0
  #pragma unroll
  for (int i = 0; i < 4; ++i) {
    int row = w * 32 + i * 8;
    gload_lds16(AO + (size_t)(m0 + row + brlane) * NDM + bce, &As[0][row][0]);
    gload_lds16(wob + (size_t)(n0 + row + brlane) * NDM + bce, &Bs[0][row][0]);
  }
  __syncthreads();

  for (int t = 0; t < 16; ++t) {
    int cur = t & 1, nxt = cur ^ 1;
    if (t < 15) {  // stage t+1 early; MFMA below hides the latency
      int k1 = (t + 1) * 64;
      #pragma unroll
      for (int i = 0; i < 4; ++i) {
        int row = w * 32 + i * 8;
        gload_lds16(AO + (size_t)(m0 + row + brlane) * NDM + k1 + bce,
                    &As[nxt][row][0]);
        gload_lds16(wob + (size_t)(n0 + row + brlane) * NDM + k1 + bce,
                    &Bs[nxt][row][0]);
      }
    }

    #pragma unroll
    for (int kc = 0; kc < 2; ++kc) {
      bf16x8 af[4], bf[4];
      #pragma unroll
      for (int i = 0; i < 4; ++i) {
        int gran = (kc * 4 + g) ^ (r16 & 7);
        af[i] = *(const bf16x8*)&As[cur][wm * 64 + i * 16 + r16][gran * 8];
        bf[i] = *(const bf16x8*)&Bs[cur][wn * 64 + i * 16 + r16][gran * 8];
      }
      #pragma unroll
      for (int mi = 0; mi < 4; ++mi)
        #pragma unroll
        for (int ni = 0; ni < 4; ++ni)
          acc[mi][ni] = __builtin_amdgcn_mfma_f32_16x16x32_bf16(
              af[mi], bf[ni], acc[mi][ni], 0, 0, 0);
    }
    __syncthreads();
  }

  #pragma unroll
  for (int mi = 0; mi < 4; ++mi) {
    #pragma unroll
    for (int ni = 0; ni < 4; ++ni) {
      int m = m0 + wm * 64 + mi * 16 + g * 4;
      int n = n0 + wn * 64 + ni * 16 + r16;
      #pragma unroll
      for (int j = 0; j < 4; ++j)
        out[(size_t)(m + j) * NDM + n] = acc[mi][ni][j];
    }
  }
}

extern "C" void kernel_launch(void* const* d_in, const int* in_sizes, int n_in,
                              void* d_out, int out_size, void* d_ws,
                              size_t ws_size, hipStream_t stream) {
  const float* q  = (const float*)d_in[0];
  const float* k  = (const float*)d_in[1];
  const float* v  = (const float*)d_in[2];
  const float* wq = (const float*)d_in[3];
  const float* wk = (const float*)d_in[4];
  const float* wv = (const float*)d_in[5];
  const float* wo = (const float*)d_in[6];

  uint16_t* XQ  = (uint16_t*)d_ws;                 // [NTOK][NDM] bf16
  uint16_t* XK  = XQ + (size_t)NTOK * NDM;         // [NTOK][NDM]
  uint16_t* XVT = XK + (size_t)NTOK * NDM;         // [NDM][NTOK]
  uint16_t* AO  = XVT + (size_t)NTOK * NDM;        // [NTOK][NDM]
  uint16_t* WQB = AO + (size_t)NTOK * NDM;         // [NDM][NDM] bf16 weights
  uint16_t* WKB = WQB + (size_t)NDM * NDM;
  uint16_t* WVB = WKB + (size_t)NDM * NDM;
  uint16_t* WOB = WVB + (size_t)NDM * NDM;
  // total ws use: 40 MiB

  cvt_w<<<dim3(NDM * NDM / (256 * 8), 4), 256, 0, stream>>>(
      wq, wk, wv, wo, WQB, WKB, WVB, WOB);
  proj_gemm<<<dim3(NTOK / 128, NDM / 128, 3), 256, 0, stream>>>(
      q, k, v, WQB, WKB, WVB, XQ, XK, XVT);
  attn_kernel<<<dim3(1024), 256, 0, stream>>>(XQ, XK, XVT, AO);
  out_gemm<<<dim3(NTOK / 128, NDM / 128), 256, 0, stream>>>(
      AO, WOB, (float*)d_out);
}